// Round 5
// baseline (2628.503 us; speedup 1.0000x reference)
//
#include <hip/hip_runtime.h>

typedef _Float16 half_t;
typedef _Float16 half4 __attribute__((ext_vector_type(4)));
typedef _Float16 half8 __attribute__((ext_vector_type(8)));
typedef float floatx4 __attribute__((ext_vector_type(4)));
typedef unsigned long long ull_t;

#define SEQ 256
#define BATCH 64
#define EMB 256
#define HID 512
#define NOUT 18
#define M_TOT (SEQ*BATCH)   // 16384

// rnn_layer geometry (round 7: full W in regs, h dbuf, 1 barrier/step)
#define HROW 520             // LDS h row stride in halfs (512 + 8 pad)

// ---------------- ws layout (bytes) ----------------
#define O_WHH0_16 0u          // 2*512*512 half = 1048576
#define O_WHH1_16 1048576u    // 1048576
#define O_EMFC16  2097152u    // 65536 half = 131072
#define O_WIH0    2228224u    // 1024*256 half = 524288
#define O_WIH1    2752512u    // 1024*1024 half = 2097152
#define O_FC16    4849664u    // 18*1024 half = 36864
#define O_PE      4886528u    // post_emb 16384*256 half = 8388608
#define O_XP      13275136u   // xp 16384*1024 half = 33554432 (shared by layer0/layer1)
#define O_OUT     46829568u   // 16384*1024 half (out0/out1 aliased; stream-ordered safe)
// total 80384000 bytes

// ---------------- fp32 -> fp16 convert (8 elems/thread) ----------------
__global__ void cvt_f32f16(const float* __restrict__ s, half_t* __restrict__ d, int n8) {
    int i = blockIdx.x * 256 + threadIdx.x;
    if (i < n8) {
        const float4* s4 = (const float4*)s;
        float4 a = s4[2*i], b = s4[2*i+1];
        half8 h;
        h[0]=(_Float16)a.x; h[1]=(_Float16)a.y; h[2]=(_Float16)a.z; h[3]=(_Float16)a.w;
        h[4]=(_Float16)b.x; h[5]=(_Float16)b.y; h[6]=(_Float16)b.z; h[7]=(_Float16)b.w;
        *(half8*)(d + (size_t)i*8) = h;
    }
}

// ---------------- generic NT GEMM: C[m,n] = sum_k A[m,k]*B[n,k] + bias ----------------
template<bool GATHER>
__global__ __launch_bounds__(256)
void gemm_nt(const half_t* __restrict__ A, const float* __restrict__ Atab,
             const int* __restrict__ gidx, const half_t* __restrict__ Bm,
             const float* __restrict__ bias0, const float* __restrict__ bias1,
             half_t* __restrict__ Cout, int M, int N, int K)
{
    __shared__ half8 As8[512];   // 128 x 32 half
    __shared__ half8 Bs8[512];
    half_t* As = (half_t*)As8;
    half_t* Bs = (half_t*)Bs8;

    const int tid  = threadIdx.x;
    const int lane = tid & 63, wid = tid >> 6;
    const int wm = wid >> 1, wn = wid & 1;
    const int ln = lane & 15, hi = lane >> 4;
    const int m0 = blockIdx.x * 128, n0 = blockIdx.y * 128;

    floatx4 acc[4][4] = {};
    const int kTiles = K >> 5;

    for (int kt = 0; kt < kTiles; ++kt) {
        if constexpr (GATHER) {
            int r = tid >> 1, q = tid & 1;
            int row = gidx[m0 + r];
            const float* src = Atab + (size_t)row * EMB + kt*32 + q*16;
            float4 f0 = *(const float4*)(src);
            float4 f1 = *(const float4*)(src + 4);
            float4 f2 = *(const float4*)(src + 8);
            float4 f3 = *(const float4*)(src + 12);
            half8 h0, h1;
            h0[0]=(_Float16)f0.x; h0[1]=(_Float16)f0.y; h0[2]=(_Float16)f0.z; h0[3]=(_Float16)f0.w;
            h0[4]=(_Float16)f1.x; h0[5]=(_Float16)f1.y; h0[6]=(_Float16)f1.z; h0[7]=(_Float16)f1.w;
            h1[0]=(_Float16)f2.x; h1[1]=(_Float16)f2.y; h1[2]=(_Float16)f2.z; h1[3]=(_Float16)f2.w;
            h1[4]=(_Float16)f3.x; h1[5]=(_Float16)f3.y; h1[6]=(_Float16)f3.z; h1[7]=(_Float16)f3.w;
            int c0 = 2*q, c1 = 2*q + 1;
            *(half8*)(As + r*32 + (((c0 + (r>>1)) & 3) * 8)) = h0;
            *(half8*)(As + r*32 + (((c1 + (r>>1)) & 3) * 8)) = h1;
        } else {
            #pragma unroll
            for (int ii = 0; ii < 2; ++ii) {
                int ch = tid + ii*256; int r = ch >> 2, c = ch & 3;
                half8 v = *(const half8*)(A + (size_t)(m0+r)*K + kt*32 + c*8);
                *(half8*)(As + r*32 + (((c + (r>>1)) & 3) * 8)) = v;
            }
        }
        #pragma unroll
        for (int ii = 0; ii < 2; ++ii) {
            int ch = tid + ii*256; int r = ch >> 2, c = ch & 3;
            half8 v = *(const half8*)(Bm + (size_t)(n0+r)*K + kt*32 + c*8);
            *(half8*)(Bs + r*32 + (((c + (r>>1)) & 3) * 8)) = v;
        }
        __syncthreads();

        half8 af[4], bf[4];
        #pragma unroll
        for (int mt = 0; mt < 4; ++mt) {
            int r = wm*64 + mt*16 + ln;
            af[mt] = *(const half8*)(As + r*32 + ((hi + (r>>1)) & 3) * 8);
        }
        #pragma unroll
        for (int nt = 0; nt < 4; ++nt) {
            int r = wn*64 + nt*16 + ln;
            bf[nt] = *(const half8*)(Bs + r*32 + ((hi + (r>>1)) & 3) * 8);
        }
        #pragma unroll
        for (int mt = 0; mt < 4; ++mt)
            #pragma unroll
            for (int nt = 0; nt < 4; ++nt)
                acc[mt][nt] = __builtin_amdgcn_mfma_f32_16x16x32_f16(af[mt], bf[nt], acc[mt][nt], 0, 0, 0);
        __syncthreads();
    }

    #pragma unroll
    for (int mt = 0; mt < 4; ++mt) {
        #pragma unroll
        for (int nt = 0; nt < 4; ++nt) {
            int n = n0 + wn*64 + nt*16 + ln;
            float bv = (bias0 ? bias0[n] : 0.f) + (bias1 ? bias1[n] : 0.f);
            #pragma unroll
            for (int r = 0; r < 4; ++r) {
                int m = m0 + wm*64 + mt*16 + hi*4 + r;
                Cout[(size_t)m*N + n] = (half_t)(acc[mt][nt][r] + bv);
            }
        }
    }
}

// ---------------- persistent bidirectional RNN layer (round 7: all-reg W) ----------------
// grid = 8 blocks (2 dir x 4 batch-groups) x 512 thr (8 waves, 2 per SIMD).
// Round-4 post-mortem: VGPR_Count=128 proved ~128 regs of headroom -> the ENTIRE W row
// set fits in registers: afrag[4][16] = 128 regs/thread (wave owns 64 j, all 512 k).
// Consequences: no wlds (LDS read traffic halves to ~144KB/step, under the 2480cy MFMA
// floor), LDS shrinks to a 33KB static h double-buffer, and dbuf needs only ONE
// barrier/step (end-of-step barrier both publishes h(t+1) writes and proves all reads
// of the other buffer completed). MFMA pipe becomes the limiting resource (~2480cy/step).
__global__ __launch_bounds__(512, 2)
void rnn_layer(const half_t* __restrict__ xp, half_t* __restrict__ outbuf,
               const half_t* __restrict__ whh16)
{
    __shared__ half_t hlds[2][16][HROW];   // 33280 B

    const int bid = blockIdx.x;
    const int dir = bid >> 2;
    const int bg  = bid & 3;
    const int w   = threadIdx.x >> 6;      // wave 0..7, owns j in [w*64, w*64+64)
    const int lane = threadIdx.x & 63;
    const int ln = lane & 15, hi = lane >> 4;

    const half_t* wbase = whh16 + (size_t)dir * HID * HID;

    // A fragments in regs: afrag[mt][kk] = W[w*64+mt*16+ln][kk*32+hi*8 ..+8] — ALL k.
    half8 afrag[4][16];
    #pragma unroll
    for (int mt = 0; mt < 4; ++mt) {
        #pragma unroll
        for (int kk = 0; kk < 16; ++kk)
            afrag[mt][kk] = *(const half8*)(wbase + (size_t)(w*64 + mt*16 + ln)*HID + kk*32 + hi*8);
    }

    const int b  = bg*16 + ln;       // this lane's batch column
    const int jq = w*64 + hi*4;      // j quad base; mt adds 16

    const ptrdiff_t dstep = dir ? -(ptrdiff_t)(BATCH*2*HID) : (ptrdiff_t)(BATCH*2*HID);
    const int t0 = dir ? (SEQ-1) : 0;
    const size_t base0 = ((size_t)(t0*BATCH + b))*(2*HID) + (size_t)dir*HID + jq;
    const half_t* xb = xp + base0;
    half_t*       op = outbuf + base0;

    // per-lane LDS bases (buffer selected by +buf*16*HROW)
    const half_t* hrd0 = &hlds[0][ln][hi*8];   // + rb*16*HROW + kk*32
    half_t*       hwr0 = &hlds[0][ln][jq];     // + wb*16*HROW + mt*16

    // ---- step 0: h == 0 -> acc = xq(t0); no h reads, no MFMA ----
    half4 xq[4];
    #pragma unroll
    for (int mt = 0; mt < 4; ++mt) xq[mt] = *(const half4*)(xb + mt*16);
    xb += dstep;

    floatx4 acc[4];
    #pragma unroll
    for (int mt = 0; mt < 4; ++mt) {
        acc[mt][0] = (float)xq[mt][0]; acc[mt][1] = (float)xq[mt][1];
        acc[mt][2] = (float)xq[mt][2]; acc[mt][3] = (float)xq[mt][3];
    }
    // prefetch xq(t1)
    #pragma unroll
    for (int mt = 0; mt < 4; ++mt) xq[mt] = *(const half4*)(xb + mt*16);
    xb += dstep;

    {
        half4 hv[4];
        #pragma unroll
        for (int mt = 0; mt < 4; ++mt) {
            #pragma unroll
            for (int r = 0; r < 4; ++r)
                hv[mt][r] = (_Float16)fmaxf(acc[mt][r], 0.f);
            *(half4*)(hwr0 + mt*16) = hv[mt];     // buffer 0 holds h(t=0+1 input), i.e. h after step0
            *(half4*)(op  + mt*16) = hv[mt];
        }
        op += dstep;
    }
    // publish step-0 h writes
    asm volatile("s_waitcnt lgkmcnt(0)\n\ts_barrier" ::: "memory");

    for (int step = 1; step < SEQ; ++step) {
        // rb: buffer holding h produced by step-1; wb: buffer for h of this step
        const int rb = (step + 1) & 1;   // step1 reads buf0 (written in step0)
        const int wb = step & 1;
        const half_t* hrd = hrd0 + (size_t)rb*16*HROW;

        // seed acc from prefetched xq; issue next prefetch (lands under MFMA phase)
        #pragma unroll
        for (int mt = 0; mt < 4; ++mt) {
            acc[mt][0] = (float)xq[mt][0]; acc[mt][1] = (float)xq[mt][1];
            acc[mt][2] = (float)xq[mt][2]; acc[mt][3] = (float)xq[mt][3];
        }
        if (step + 1 < SEQ) {
            #pragma unroll
            for (int mt = 0; mt < 4; ++mt) xq[mt] = *(const half4*)(xb + mt*16);
        }
        xb += dstep;

        __builtin_amdgcn_s_setprio(1);
        // ---- all 512 k: W in regs, h from LDS (2-deep paired pipeline) ----
        half8 c0 = *(const half8*)(hrd + 0*32);
        half8 c1 = *(const half8*)(hrd + 1*32);
        #pragma unroll
        for (int g = 0; g < 7; ++g) {
            half8 n0 = *(const half8*)(hrd + (2*g+2)*32);
            half8 n1 = *(const half8*)(hrd + (2*g+3)*32);
            #pragma unroll
            for (int mt = 0; mt < 4; ++mt)
                acc[mt] = __builtin_amdgcn_mfma_f32_16x16x32_f16(afrag[mt][2*g],   c0, acc[mt], 0, 0, 0);
            #pragma unroll
            for (int mt = 0; mt < 4; ++mt)
                acc[mt] = __builtin_amdgcn_mfma_f32_16x16x32_f16(afrag[mt][2*g+1], c1, acc[mt], 0, 0, 0);
            c0 = n0; c1 = n1;
        }
        #pragma unroll
        for (int mt = 0; mt < 4; ++mt)
            acc[mt] = __builtin_amdgcn_mfma_f32_16x16x32_f16(afrag[mt][14], c0, acc[mt], 0, 0, 0);
        #pragma unroll
        for (int mt = 0; mt < 4; ++mt)
            acc[mt] = __builtin_amdgcn_mfma_f32_16x16x32_f16(afrag[mt][15], c1, acc[mt], 0, 0, 0);
        __builtin_amdgcn_s_setprio(0);

        // ---- epilogue: hv = relu(acc) ----
        half4 hv[4];
        #pragma unroll
        for (int mt = 0; mt < 4; ++mt) {
            #pragma unroll
            for (int r = 0; r < 4; ++r)
                hv[mt][r] = (_Float16)fmaxf(acc[mt][r], 0.f);
        }

        if (step + 1 < SEQ) {
            half_t* hw = hwr0 + (size_t)wb*16*HROW;
            #pragma unroll
            for (int mt = 0; mt < 4; ++mt)
                *(half4*)(hw + mt*16) = hv[mt];
            // single barrier: publishes h(t+1) AND proves all reads of rb finished
            asm volatile("s_waitcnt lgkmcnt(0)\n\ts_barrier" ::: "memory");
        }

        // fire-and-forget global store (drained at kernel end)
        #pragma unroll
        for (int mt = 0; mt < 4; ++mt)
            *(half4*)(op + mt*16) = hv[mt];
        op += dstep;
    }
}

// ---------------- final FC: [16384,1024] x [18,1024]^T + b ----------------
__global__ __launch_bounds__(256)
void fc_kernel(const half_t* __restrict__ X, const half_t* __restrict__ W16,
               const float* __restrict__ bias, float* __restrict__ Y)
{
    __shared__ half8 Ws8[2304];   // 18*1024 half
    half_t* Ws = (half_t*)Ws8;
    for (int ch = threadIdx.x; ch < 2304; ch += 256)
        Ws8[ch] = *(const half8*)(W16 + (size_t)ch*8);
    __syncthreads();

    int wi = threadIdx.x >> 6, lane = threadIdx.x & 63;
    int m = blockIdx.x*4 + wi;
    const half_t* xr = X + (size_t)m*1024 + lane*16;
    half8 x0 = *(const half8*)xr;
    half8 x1 = *(const half8*)(xr + 8);
    float xa[16];
    #pragma unroll
    for (int i = 0; i < 8; ++i) { xa[i] = (float)x0[i]; xa[8+i] = (float)x1[i]; }

    for (int n = 0; n < NOUT; ++n) {
        const half_t* wr = Ws + n*1024 + lane*16;
        half8 w0 = *(const half8*)wr;
        half8 w1 = *(const half8*)(wr + 8);
        float s = 0.f;
        #pragma unroll
        for (int i = 0; i < 8; ++i) s += xa[i]*(float)w0[i] + xa[8+i]*(float)w1[i];
        #pragma unroll
        for (int off = 32; off > 0; off >>= 1) s += __shfl_down(s, off, 64);
        if (lane == 0) Y[(size_t)m*NOUT + n] = s + bias[n];
    }
}

// ---------------- launcher ----------------
extern "C" void kernel_launch(void* const* d_in, const int* in_sizes, int n_in,
                              void* d_out, int out_size, void* d_ws, size_t ws_size,
                              hipStream_t stream)
{
    const int*   text    = (const int*)  d_in[0];
    const float* emb     = (const float*)d_in[1];
    const float* emfc_w  = (const float*)d_in[2];
    const float* emfc_b  = (const float*)d_in[3];
    const float* w_ih0   = (const float*)d_in[4];
    const float* w_hh0   = (const float*)d_in[5];
    const float* b_ih0   = (const float*)d_in[6];
    const float* b_hh0   = (const float*)d_in[7];
    const float* w_ih1   = (const float*)d_in[8];
    const float* w_hh1   = (const float*)d_in[9];
    const float* b_ih1   = (const float*)d_in[10];
    const float* b_hh1   = (const float*)d_in[11];
    const float* fc_w    = (const float*)d_in[12];
    const float* fc_b    = (const float*)d_in[13];
    float* out = (float*)d_out;

    char* ws = (char*)d_ws;
    half_t* whh0_16 = (half_t*)(ws + O_WHH0_16);
    half_t* whh1_16 = (half_t*)(ws + O_WHH1_16);
    half_t* emfc16  = (half_t*)(ws + O_EMFC16);
    half_t* wih0    = (half_t*)(ws + O_WIH0);
    half_t* wih1    = (half_t*)(ws + O_WIH1);
    half_t* fc16    = (half_t*)(ws + O_FC16);
    half_t* pe      = (half_t*)(ws + O_PE);
    half_t* xp      = (half_t*)(ws + O_XP);
    half_t* out0    = (half_t*)(ws + O_OUT);
    half_t* out1    = (half_t*)(ws + O_OUT);   // aliased: out0 dead once xp1 GEMM done

    // 1) weight conversions fp32->fp16
    cvt_f32f16<<<32,  256, 0, stream>>>(emfc_w, emfc16, 8192);
    cvt_f32f16<<<128, 256, 0, stream>>>(w_ih0,  wih0,  32768);
    cvt_f32f16<<<512, 256, 0, stream>>>(w_ih1,  wih1, 131072);
    cvt_f32f16<<<256, 256, 0, stream>>>(w_hh0,  whh0_16, 65536);
    cvt_f32f16<<<256, 256, 0, stream>>>(w_hh1,  whh1_16, 65536);
    cvt_f32f16<<<9,   256, 0, stream>>>(fc_w,   fc16,   2304);

    // 2) post_emb = gather(emb, text) @ emfc_w^T + emfc_b
    gemm_nt<true><<<dim3(M_TOT/128, EMB/128), 256, 0, stream>>>(
        nullptr, emb, text, emfc16, emfc_b, nullptr, pe, M_TOT, EMB, EMB);

    // 3) xp0 = post_emb @ w_ih0^T + (b_ih0 + b_hh0)
    gemm_nt<false><<<dim3(M_TOT/128, (2*HID)/128), 256, 0, stream>>>(
        pe, nullptr, nullptr, wih0, b_ih0, b_hh0, xp, M_TOT, 2*HID, EMB);

    // 4) layer0 recurrence (8 independent blocks x 8 waves)
    rnn_layer<<<8, 512, 0, stream>>>(xp, out0, whh0_16);

    // 5) xp1 = out0 @ w_ih1^T + (b_ih1 + b_hh1)
    gemm_nt<false><<<dim3(M_TOT/128, (2*HID)/128), 256, 0, stream>>>(
        out0, nullptr, nullptr, wih1, b_ih1, b_hh1, xp, M_TOT, 2*HID, 2*HID);

    // 6) layer1 recurrence
    rnn_layer<<<8, 512, 0, stream>>>(xp, out1, whh1_16);

    // 7) out = out1 @ fc_w^T + fc_b
    fc_kernel<<<M_TOT/4, 256, 0, stream>>>(out1, fc16, fc_b, out);
}

// Round 6
// 2180.266 us; speedup vs baseline: 1.2056x; 1.2056x over previous
//
#include <hip/hip_runtime.h>

typedef _Float16 half_t;
typedef _Float16 half4 __attribute__((ext_vector_type(4)));
typedef _Float16 half8 __attribute__((ext_vector_type(8)));
typedef float floatx4 __attribute__((ext_vector_type(4)));
typedef unsigned long long ull_t;

#define SEQ 256
#define BATCH 64
#define EMB 256
#define HID 512
#define NOUT 18
#define M_TOT (SEQ*BATCH)   // 16384

// rnn_layer geometry (round 8: R4 register split + single-barrier dbuf + XOR swizzle)
#define KK_REG 12            // K-tiles (of 32) in registers: k < 384  (192 regs -> fits at 2 w/SIMD)
#define K_REG  (KK_REG*32)   // 384
#define WTILE_BYTES (HID*256)         // wlds [512][128 halfs] = 131072 B (swizzled, no pad)
#define HBUF_BYTES  (16*1024)         // one h buffer [16][512 halfs] = 16384 B (swizzled)
#define LDS_BYTES (WTILE_BYTES + 2*HBUF_BYTES)  // 163840 = full 160 KiB

// ---------------- ws layout (bytes) ----------------
#define O_WHH0_16 0u          // 2*512*512 half = 1048576
#define O_WHH1_16 1048576u    // 1048576
#define O_EMFC16  2097152u    // 65536 half = 131072
#define O_WIH0    2228224u    // 1024*256 half = 524288
#define O_WIH1    2752512u    // 1024*1024 half = 2097152
#define O_FC16    4849664u    // 18*1024 half = 36864
#define O_PE      4886528u    // post_emb 16384*256 half = 8388608
#define O_XP      13275136u   // xp 16384*1024 half = 33554432 (shared by layer0/layer1)
#define O_OUT     46829568u   // 16384*1024 half (out0/out1 aliased; stream-ordered safe)
// total 80384000 bytes

// ---------------- fp32 -> fp16 convert (8 elems/thread) ----------------
__global__ void cvt_f32f16(const float* __restrict__ s, half_t* __restrict__ d, int n8) {
    int i = blockIdx.x * 256 + threadIdx.x;
    if (i < n8) {
        const float4* s4 = (const float4*)s;
        float4 a = s4[2*i], b = s4[2*i+1];
        half8 h;
        h[0]=(_Float16)a.x; h[1]=(_Float16)a.y; h[2]=(_Float16)a.z; h[3]=(_Float16)a.w;
        h[4]=(_Float16)b.x; h[5]=(_Float16)b.y; h[6]=(_Float16)b.z; h[7]=(_Float16)b.w;
        *(half8*)(d + (size_t)i*8) = h;
    }
}

// ---------------- generic NT GEMM: C[m,n] = sum_k A[m,k]*B[n,k] + bias ----------------
template<bool GATHER>
__global__ __launch_bounds__(256)
void gemm_nt(const half_t* __restrict__ A, const float* __restrict__ Atab,
             const int* __restrict__ gidx, const half_t* __restrict__ Bm,
             const float* __restrict__ bias0, const float* __restrict__ bias1,
             half_t* __restrict__ Cout, int M, int N, int K)
{
    __shared__ half8 As8[512];   // 128 x 32 half
    __shared__ half8 Bs8[512];
    half_t* As = (half_t*)As8;
    half_t* Bs = (half_t*)Bs8;

    const int tid  = threadIdx.x;
    const int lane = tid & 63, wid = tid >> 6;
    const int wm = wid >> 1, wn = wid & 1;
    const int ln = lane & 15, hi = lane >> 4;
    const int m0 = blockIdx.x * 128, n0 = blockIdx.y * 128;

    floatx4 acc[4][4] = {};
    const int kTiles = K >> 5;

    for (int kt = 0; kt < kTiles; ++kt) {
        if constexpr (GATHER) {
            int r = tid >> 1, q = tid & 1;
            int row = gidx[m0 + r];
            const float* src = Atab + (size_t)row * EMB + kt*32 + q*16;
            float4 f0 = *(const float4*)(src);
            float4 f1 = *(const float4*)(src + 4);
            float4 f2 = *(const float4*)(src + 8);
            float4 f3 = *(const float4*)(src + 12);
            half8 h0, h1;
            h0[0]=(_Float16)f0.x; h0[1]=(_Float16)f0.y; h0[2]=(_Float16)f0.z; h0[3]=(_Float16)f0.w;
            h0[4]=(_Float16)f1.x; h0[5]=(_Float16)f1.y; h0[6]=(_Float16)f1.z; h0[7]=(_Float16)f1.w;
            h1[0]=(_Float16)f2.x; h1[1]=(_Float16)f2.y; h1[2]=(_Float16)f2.z; h1[3]=(_Float16)f2.w;
            h1[4]=(_Float16)f3.x; h1[5]=(_Float16)f3.y; h1[6]=(_Float16)f3.z; h1[7]=(_Float16)f3.w;
            int c0 = 2*q, c1 = 2*q + 1;
            *(half8*)(As + r*32 + (((c0 + (r>>1)) & 3) * 8)) = h0;
            *(half8*)(As + r*32 + (((c1 + (r>>1)) & 3) * 8)) = h1;
        } else {
            #pragma unroll
            for (int ii = 0; ii < 2; ++ii) {
                int ch = tid + ii*256; int r = ch >> 2, c = ch & 3;
                half8 v = *(const half8*)(A + (size_t)(m0+r)*K + kt*32 + c*8);
                *(half8*)(As + r*32 + (((c + (r>>1)) & 3) * 8)) = v;
            }
        }
        #pragma unroll
        for (int ii = 0; ii < 2; ++ii) {
            int ch = tid + ii*256; int r = ch >> 2, c = ch & 3;
            half8 v = *(const half8*)(Bm + (size_t)(n0+r)*K + kt*32 + c*8);
            *(half8*)(Bs + r*32 + (((c + (r>>1)) & 3) * 8)) = v;
        }
        __syncthreads();

        half8 af[4], bf[4];
        #pragma unroll
        for (int mt = 0; mt < 4; ++mt) {
            int r = wm*64 + mt*16 + ln;
            af[mt] = *(const half8*)(As + r*32 + ((hi + (r>>1)) & 3) * 8);
        }
        #pragma unroll
        for (int nt = 0; nt < 4; ++nt) {
            int r = wn*64 + nt*16 + ln;
            bf[nt] = *(const half8*)(Bs + r*32 + ((hi + (r>>1)) & 3) * 8);
        }
        #pragma unroll
        for (int mt = 0; mt < 4; ++mt)
            #pragma unroll
            for (int nt = 0; nt < 4; ++nt)
                acc[mt][nt] = __builtin_amdgcn_mfma_f32_16x16x32_f16(af[mt], bf[nt], acc[mt][nt], 0, 0, 0);
        __syncthreads();
    }

    #pragma unroll
    for (int mt = 0; mt < 4; ++mt) {
        #pragma unroll
        for (int nt = 0; nt < 4; ++nt) {
            int n = n0 + wn*64 + nt*16 + ln;
            float bv = (bias0 ? bias0[n] : 0.f) + (bias1 ? bias1[n] : 0.f);
            #pragma unroll
            for (int r = 0; r < 4; ++r) {
                int m = m0 + wm*64 + mt*16 + hi*4 + r;
                Cout[(size_t)m*N + n] = (half_t)(acc[mt][nt][r] + bv);
            }
        }
    }
}

// ---------------- persistent bidirectional RNN layer (round 8) ----------------
// grid = 8 blocks (2 dir x 4 batch-groups) x 512 thr (8 waves, 2 per SIMD).
// Register split PROVEN in round 4 (593us): afrag[4][12] = 192 regs + ~50 live = 241,
// fits the 256-reg unified budget at 2 waves/SIMD (round-5 lesson: [4][16]=256 regs spills).
// Round-6 change ISOLATED: h double-buffer + ONE barrier/step (round 4 had 2/step).
// LDS capacity solved by XOR swizzle instead of pad: wlds [512][128] linear (131072B) and
// h [2][16][512] linear (32768B) = exactly 163840B; all reads/writes XOR byte ^ (ln&7)<<4
// (row&7 == ln&7 on both producer and consumer sides -> consistent, bijective per row,
// preserves 16B/8B alignment, conflict profile same as the +8-half pad it replaces).
__global__ __launch_bounds__(512, 2)
void rnn_layer(const half_t* __restrict__ xp, half_t* __restrict__ outbuf,
               const half_t* __restrict__ whh16)
{
    extern __shared__ char smem[];
    char* wlds = smem;                    // [512 rows][256 B] W k-tail, swizzled
    char* hlds = smem + WTILE_BYTES;      // [2 buf][16 rows][1024 B] h, swizzled

    const int bid = blockIdx.x;
    const int dir = bid >> 2;
    const int bg  = bid & 3;
    const int w   = threadIdx.x >> 6;      // wave 0..7, owns j in [w*64, w*64+64)
    const int lane = threadIdx.x & 63;
    const int ln = lane & 15, hi = lane >> 4;
    const int sw = (ln & 7) << 4;          // per-lane XOR swizzle (bits 4-6)

    const half_t* wbase = whh16 + (size_t)dir * HID * HID;

    // A fragments in regs: afrag[mt][kk] = W[w*64+mt*16+ln][kk*32+hi*8 ..+8], kk<12
    half8 afrag[4][KK_REG];
    #pragma unroll
    for (int mt = 0; mt < 4; ++mt) {
        #pragma unroll
        for (int kk = 0; kk < KK_REG; ++kk)
            afrag[mt][kk] = *(const half8*)(wbase + (size_t)(w*64 + mt*16 + ln)*HID + kk*32 + hi*8);
    }

    // stage W k-tail [384,512) into LDS: 512 rows x 16 half8, swizzled
    for (int idx = threadIdx.x; idx < HID*16; idx += 512) {
        int row = idx >> 4, c8 = idx & 15;
        *(half8*)(wlds + row*256 + ((c8*16) ^ ((row & 7) << 4))) =
            *(const half8*)(wbase + (size_t)row*HID + K_REG + c8*8);
    }

    const int b  = bg*16 + ln;       // this lane's batch column
    const int jq = w*64 + hi*4;      // j quad base; mt adds 16

    const ptrdiff_t dstep = dir ? -(ptrdiff_t)(BATCH*2*HID) : (ptrdiff_t)(BATCH*2*HID);
    const int t0 = dir ? (SEQ-1) : 0;
    const size_t base0 = ((size_t)(t0*BATCH + b))*(2*HID) + (size_t)dir*HID + jq;
    const half_t* xb = xp + base0;
    half_t*       op = outbuf + base0;

    // per-lane LDS byte bases
    //   h read  (row=ln): hlds + rb*HBUF + ln*1024 + ((kk*64 + hi*16) ^ sw)
    //   h write (row=ln): hlds + wb*HBUF + ln*1024 + ((w*128 + hi*8 + mt*32) ^ sw)
    //   W read  (row=w*64+mt*16+ln, row&7==ln&7): wlds + row*256 + ((kt*64 + hi*16) ^ sw)
    char* hrow = hlds + ln*1024;
    char* wrow = wlds + (w*64 + ln)*256;

    // ---- step 0: h == 0 -> acc = xq(t0); no h reads, no MFMA ----
    half4 xq[4];
    #pragma unroll
    for (int mt = 0; mt < 4; ++mt) xq[mt] = *(const half4*)(xb + mt*16);
    xb += dstep;

    floatx4 acc[4];
    #pragma unroll
    for (int mt = 0; mt < 4; ++mt) {
        acc[mt][0] = (float)xq[mt][0]; acc[mt][1] = (float)xq[mt][1];
        acc[mt][2] = (float)xq[mt][2]; acc[mt][3] = (float)xq[mt][3];
    }
    // prefetch xq(t1)
    #pragma unroll
    for (int mt = 0; mt < 4; ++mt) xq[mt] = *(const half4*)(xb + mt*16);
    xb += dstep;

    {
        half4 hv[4];
        #pragma unroll
        for (int mt = 0; mt < 4; ++mt) {
            #pragma unroll
            for (int r = 0; r < 4; ++r)
                hv[mt][r] = (_Float16)fmaxf(acc[mt][r], 0.f);
            *(half4*)(hrow + ((w*128 + hi*8 + mt*32) ^ sw)) = hv[mt];   // buffer 0
            *(half4*)(op + mt*16) = hv[mt];
        }
        op += dstep;
    }
    // publish wlds staging + step-0 h writes
    asm volatile("s_waitcnt lgkmcnt(0)\n\ts_barrier" ::: "memory");

    for (int step = 1; step < SEQ; ++step) {
        const int rb = (step + 1) & 1;   // buffer holding h from previous step
        const int wb = step & 1;         // buffer to write h of this step
        const char* hrd = hrow + rb*HBUF_BYTES;

        // seed acc from prefetched xq; issue next prefetch (lands under MFMA phase)
        #pragma unroll
        for (int mt = 0; mt < 4; ++mt) {
            acc[mt][0] = (float)xq[mt][0]; acc[mt][1] = (float)xq[mt][1];
            acc[mt][2] = (float)xq[mt][2]; acc[mt][3] = (float)xq[mt][3];
        }
        if (step + 1 < SEQ) {
            #pragma unroll
            for (int mt = 0; mt < 4; ++mt) xq[mt] = *(const half4*)(xb + mt*16);
        }
        xb += dstep;

        __builtin_amdgcn_s_setprio(1);
        // ---- k < 384: W in regs, h from LDS (2-deep paired pipeline) ----
        half8 c0 = *(const half8*)(hrd + ((0*64 + hi*16) ^ sw));
        half8 c1 = *(const half8*)(hrd + ((1*64 + hi*16) ^ sw));
        #pragma unroll
        for (int g = 0; g < 5; ++g) {
            half8 n0 = *(const half8*)(hrd + (((2*g+2)*64 + hi*16) ^ sw));
            half8 n1 = *(const half8*)(hrd + (((2*g+3)*64 + hi*16) ^ sw));
            #pragma unroll
            for (int mt = 0; mt < 4; ++mt)
                acc[mt] = __builtin_amdgcn_mfma_f32_16x16x32_f16(afrag[mt][2*g],   c0, acc[mt], 0, 0, 0);
            #pragma unroll
            for (int mt = 0; mt < 4; ++mt)
                acc[mt] = __builtin_amdgcn_mfma_f32_16x16x32_f16(afrag[mt][2*g+1], c1, acc[mt], 0, 0, 0);
            c0 = n0; c1 = n1;
        }
        #pragma unroll
        for (int mt = 0; mt < 4; ++mt)
            acc[mt] = __builtin_amdgcn_mfma_f32_16x16x32_f16(afrag[mt][10], c0, acc[mt], 0, 0, 0);
        #pragma unroll
        for (int mt = 0; mt < 4; ++mt)
            acc[mt] = __builtin_amdgcn_mfma_f32_16x16x32_f16(afrag[mt][11], c1, acc[mt], 0, 0, 0);

        // ---- k in [384,512): both W and h from LDS ----
        #pragma unroll
        for (int kt = 0; kt < 4; ++kt) {
            half8 ch = *(const half8*)(hrd + (((KK_REG+kt)*64 + hi*16) ^ sw));
            half8 w0 = *(const half8*)(wrow + 0*16*256 + ((kt*64 + hi*16) ^ sw));
            half8 w1 = *(const half8*)(wrow + 1*16*256 + ((kt*64 + hi*16) ^ sw));
            half8 w2 = *(const half8*)(wrow + 2*16*256 + ((kt*64 + hi*16) ^ sw));
            half8 w3 = *(const half8*)(wrow + 3*16*256 + ((kt*64 + hi*16) ^ sw));
            acc[0] = __builtin_amdgcn_mfma_f32_16x16x32_f16(w0, ch, acc[0], 0, 0, 0);
            acc[1] = __builtin_amdgcn_mfma_f32_16x16x32_f16(w1, ch, acc[1], 0, 0, 0);
            acc[2] = __builtin_amdgcn_mfma_f32_16x16x32_f16(w2, ch, acc[2], 0, 0, 0);
            acc[3] = __builtin_amdgcn_mfma_f32_16x16x32_f16(w3, ch, acc[3], 0, 0, 0);
        }
        __builtin_amdgcn_s_setprio(0);

        // ---- epilogue: hv = relu(acc) ----
        half4 hv[4];
        #pragma unroll
        for (int mt = 0; mt < 4; ++mt) {
            #pragma unroll
            for (int r = 0; r < 4; ++r)
                hv[mt][r] = (_Float16)fmaxf(acc[mt][r], 0.f);
        }

        if (step + 1 < SEQ) {
            char* hw = hrow + wb*HBUF_BYTES;
            #pragma unroll
            for (int mt = 0; mt < 4; ++mt)
                *(half4*)(hw + ((w*128 + hi*8 + mt*32) ^ sw)) = hv[mt];
            // single barrier: publishes h(t+1) AND proves all reads of rb finished
            asm volatile("s_waitcnt lgkmcnt(0)\n\ts_barrier" ::: "memory");
        }

        // fire-and-forget global store (drained at kernel end)
        #pragma unroll
        for (int mt = 0; mt < 4; ++mt)
            *(half4*)(op + mt*16) = hv[mt];
        op += dstep;
    }
}

// ---------------- final FC: [16384,1024] x [18,1024]^T + b ----------------
__global__ __launch_bounds__(256)
void fc_kernel(const half_t* __restrict__ X, const half_t* __restrict__ W16,
               const float* __restrict__ bias, float* __restrict__ Y)
{
    __shared__ half8 Ws8[2304];   // 18*1024 half
    half_t* Ws = (half_t*)Ws8;
    for (int ch = threadIdx.x; ch < 2304; ch += 256)
        Ws8[ch] = *(const half8*)(W16 + (size_t)ch*8);
    __syncthreads();

    int wi = threadIdx.x >> 6, lane = threadIdx.x & 63;
    int m = blockIdx.x*4 + wi;
    const half_t* xr = X + (size_t)m*1024 + lane*16;
    half8 x0 = *(const half8*)xr;
    half8 x1 = *(const half8*)(xr + 8);
    float xa[16];
    #pragma unroll
    for (int i = 0; i < 8; ++i) { xa[i] = (float)x0[i]; xa[8+i] = (float)x1[i]; }

    for (int n = 0; n < NOUT; ++n) {
        const half_t* wr = Ws + n*1024 + lane*16;
        half8 w0 = *(const half8*)wr;
        half8 w1 = *(const half8*)(wr + 8);
        float s = 0.f;
        #pragma unroll
        for (int i = 0; i < 8; ++i) s += xa[i]*(float)w0[i] + xa[8+i]*(float)w1[i];
        #pragma unroll
        for (int off = 32; off > 0; off >>= 1) s += __shfl_down(s, off, 64);
        if (lane == 0) Y[(size_t)m*NOUT + n] = s + bias[n];
    }
}

// ---------------- launcher ----------------
extern "C" void kernel_launch(void* const* d_in, const int* in_sizes, int n_in,
                              void* d_out, int out_size, void* d_ws, size_t ws_size,
                              hipStream_t stream)
{
    const int*   text    = (const int*)  d_in[0];
    const float* emb     = (const float*)d_in[1];
    const float* emfc_w  = (const float*)d_in[2];
    const float* emfc_b  = (const float*)d_in[3];
    const float* w_ih0   = (const float*)d_in[4];
    const float* w_hh0   = (const float*)d_in[5];
    const float* b_ih0   = (const float*)d_in[6];
    const float* b_hh0   = (const float*)d_in[7];
    const float* w_ih1   = (const float*)d_in[8];
    const float* w_hh1   = (const float*)d_in[9];
    const float* b_ih1   = (const float*)d_in[10];
    const float* b_hh1   = (const float*)d_in[11];
    const float* fc_w    = (const float*)d_in[12];
    const float* fc_b    = (const float*)d_in[13];
    float* out = (float*)d_out;

    char* ws = (char*)d_ws;
    half_t* whh0_16 = (half_t*)(ws + O_WHH0_16);
    half_t* whh1_16 = (half_t*)(ws + O_WHH1_16);
    half_t* emfc16  = (half_t*)(ws + O_EMFC16);
    half_t* wih0    = (half_t*)(ws + O_WIH0);
    half_t* wih1    = (half_t*)(ws + O_WIH1);
    half_t* fc16    = (half_t*)(ws + O_FC16);
    half_t* pe      = (half_t*)(ws + O_PE);
    half_t* xp      = (half_t*)(ws + O_XP);
    half_t* out0    = (half_t*)(ws + O_OUT);
    half_t* out1    = (half_t*)(ws + O_OUT);   // aliased: out0 dead once xp1 GEMM done

    // one-time: allow full 160KB dynamic LDS for rnn_layer (host-side attr; capture-safe)
    static int attr_done = 0;
    if (!attr_done) {
        hipFuncSetAttribute((const void*)rnn_layer,
                            hipFuncAttributeMaxDynamicSharedMemorySize, LDS_BYTES);
        attr_done = 1;
    }

    // 1) weight conversions fp32->fp16
    cvt_f32f16<<<32,  256, 0, stream>>>(emfc_w, emfc16, 8192);
    cvt_f32f16<<<128, 256, 0, stream>>>(w_ih0,  wih0,  32768);
    cvt_f32f16<<<512, 256, 0, stream>>>(w_ih1,  wih1, 131072);
    cvt_f32f16<<<256, 256, 0, stream>>>(w_hh0,  whh0_16, 65536);
    cvt_f32f16<<<256, 256, 0, stream>>>(w_hh1,  whh1_16, 65536);
    cvt_f32f16<<<9,   256, 0, stream>>>(fc_w,   fc16,   2304);

    // 2) post_emb = gather(emb, text) @ emfc_w^T + emfc_b
    gemm_nt<true><<<dim3(M_TOT/128, EMB/128), 256, 0, stream>>>(
        nullptr, emb, text, emfc16, emfc_b, nullptr, pe, M_TOT, EMB, EMB);

    // 3) xp0 = post_emb @ w_ih0^T + (b_ih0 + b_hh0)
    gemm_nt<false><<<dim3(M_TOT/128, (2*HID)/128), 256, 0, stream>>>(
        pe, nullptr, nullptr, wih0, b_ih0, b_hh0, xp, M_TOT, 2*HID, EMB);

    // 4) layer0 recurrence (8 independent blocks x 8 waves)
    rnn_layer<<<8, 512, LDS_BYTES, stream>>>(xp, out0, whh0_16);

    // 5) xp1 = out0 @ w_ih1^T + (b_ih1 + b_hh1)
    gemm_nt<false><<<dim3(M_TOT/128, (2*HID)/128), 256, 0, stream>>>(
        out0, nullptr, nullptr, wih1, b_ih1, b_hh1, xp, M_TOT, 2*HID, 2*HID);

    // 6) layer1 recurrence
    rnn_layer<<<8, 512, LDS_BYTES, stream>>>(xp, out1, whh1_16);

    // 7) out = out1 @ fc_w^T + fc_b
    fc_kernel<<<M_TOT/4, 256, 0, stream>>>(out1, fc16, fc_b, out);
}

// Round 7
// 1406.522 us; speedup vs baseline: 1.8688x; 1.5501x over previous
//
#include <hip/hip_runtime.h>

typedef _Float16 half_t;
typedef _Float16 half4 __attribute__((ext_vector_type(4)));
typedef _Float16 half8 __attribute__((ext_vector_type(8)));
typedef float floatx4 __attribute__((ext_vector_type(4)));
typedef unsigned long long ull_t;

#define SEQ 256
#define BATCH 64
#define EMB 256
#define HID 512
#define NOUT 18
#define M_TOT (SEQ*BATCH)   // 16384

// rnn_layer geometry (round 9: R4 register split + k-major LDS + precomputed XOR + 1 barrier)
#define KK_REG 12            // K-tiles (of 32) in registers: k < 384  (192 regs, proven round 4)
#define K_REG  (KK_REG*32)   // 384
#define WTILE_BYTES (4*HID*64)        // wlds [4 kt][512 j][64 B] = 131072
#define HBUF_BYTES  (16*16*64)        // one h buffer [16 kk][16 b][64 B] = 16384
#define LDS_BYTES (WTILE_BYTES + 2*HBUF_BYTES)  // 163840 = full 160 KiB

// ---------------- ws layout (bytes) ----------------
#define O_WHH0_16 0u          // 2*512*512 half = 1048576
#define O_WHH1_16 1048576u    // 1048576
#define O_EMFC16  2097152u    // 65536 half = 131072
#define O_WIH0    2228224u    // 1024*256 half = 524288
#define O_WIH1    2752512u    // 1024*1024 half = 2097152
#define O_FC16    4849664u    // 18*1024 half = 36864
#define O_PE      4886528u    // post_emb 16384*256 half = 8388608
#define O_XP      13275136u   // xp 16384*1024 half = 33554432 (shared by layer0/layer1)
#define O_OUT     46829568u   // 16384*1024 half (out0/out1 aliased; stream-ordered safe)
// total 80384000 bytes

// ---------------- fp32 -> fp16 convert (8 elems/thread) ----------------
__global__ void cvt_f32f16(const float* __restrict__ s, half_t* __restrict__ d, int n8) {
    int i = blockIdx.x * 256 + threadIdx.x;
    if (i < n8) {
        const float4* s4 = (const float4*)s;
        float4 a = s4[2*i], b = s4[2*i+1];
        half8 h;
        h[0]=(_Float16)a.x; h[1]=(_Float16)a.y; h[2]=(_Float16)a.z; h[3]=(_Float16)a.w;
        h[4]=(_Float16)b.x; h[5]=(_Float16)b.y; h[6]=(_Float16)b.z; h[7]=(_Float16)b.w;
        *(half8*)(d + (size_t)i*8) = h;
    }
}

// ---------------- generic NT GEMM: C[m,n] = sum_k A[m,k]*B[n,k] + bias ----------------
template<bool GATHER>
__global__ __launch_bounds__(256)
void gemm_nt(const half_t* __restrict__ A, const float* __restrict__ Atab,
             const int* __restrict__ gidx, const half_t* __restrict__ Bm,
             const float* __restrict__ bias0, const float* __restrict__ bias1,
             half_t* __restrict__ Cout, int M, int N, int K)
{
    __shared__ half8 As8[512];   // 128 x 32 half
    __shared__ half8 Bs8[512];
    half_t* As = (half_t*)As8;
    half_t* Bs = (half_t*)Bs8;

    const int tid  = threadIdx.x;
    const int lane = tid & 63, wid = tid >> 6;
    const int wm = wid >> 1, wn = wid & 1;
    const int ln = lane & 15, hi = lane >> 4;
    const int m0 = blockIdx.x * 128, n0 = blockIdx.y * 128;

    floatx4 acc[4][4] = {};
    const int kTiles = K >> 5;

    for (int kt = 0; kt < kTiles; ++kt) {
        if constexpr (GATHER) {
            int r = tid >> 1, q = tid & 1;
            int row = gidx[m0 + r];
            const float* src = Atab + (size_t)row * EMB + kt*32 + q*16;
            float4 f0 = *(const float4*)(src);
            float4 f1 = *(const float4*)(src + 4);
            float4 f2 = *(const float4*)(src + 8);
            float4 f3 = *(const float4*)(src + 12);
            half8 h0, h1;
            h0[0]=(_Float16)f0.x; h0[1]=(_Float16)f0.y; h0[2]=(_Float16)f0.z; h0[3]=(_Float16)f0.w;
            h0[4]=(_Float16)f1.x; h0[5]=(_Float16)f1.y; h0[6]=(_Float16)f1.z; h0[7]=(_Float16)f1.w;
            h1[0]=(_Float16)f2.x; h1[1]=(_Float16)f2.y; h1[2]=(_Float16)f2.z; h1[3]=(_Float16)f2.w;
            h1[4]=(_Float16)f3.x; h1[5]=(_Float16)f3.y; h1[6]=(_Float16)f3.z; h1[7]=(_Float16)f3.w;
            int c0 = 2*q, c1 = 2*q + 1;
            *(half8*)(As + r*32 + (((c0 + (r>>1)) & 3) * 8)) = h0;
            *(half8*)(As + r*32 + (((c1 + (r>>1)) & 3) * 8)) = h1;
        } else {
            #pragma unroll
            for (int ii = 0; ii < 2; ++ii) {
                int ch = tid + ii*256; int r = ch >> 2, c = ch & 3;
                half8 v = *(const half8*)(A + (size_t)(m0+r)*K + kt*32 + c*8);
                *(half8*)(As + r*32 + (((c + (r>>1)) & 3) * 8)) = v;
            }
        }
        #pragma unroll
        for (int ii = 0; ii < 2; ++ii) {
            int ch = tid + ii*256; int r = ch >> 2, c = ch & 3;
            half8 v = *(const half8*)(Bm + (size_t)(n0+r)*K + kt*32 + c*8);
            *(half8*)(Bs + r*32 + (((c + (r>>1)) & 3) * 8)) = v;
        }
        __syncthreads();

        half8 af[4], bf[4];
        #pragma unroll
        for (int mt = 0; mt < 4; ++mt) {
            int r = wm*64 + mt*16 + ln;
            af[mt] = *(const half8*)(As + r*32 + ((hi + (r>>1)) & 3) * 8);
        }
        #pragma unroll
        for (int nt = 0; nt < 4; ++nt) {
            int r = wn*64 + nt*16 + ln;
            bf[nt] = *(const half8*)(Bs + r*32 + ((hi + (r>>1)) & 3) * 8);
        }
        #pragma unroll
        for (int mt = 0; mt < 4; ++mt)
            #pragma unroll
            for (int nt = 0; nt < 4; ++nt)
                acc[mt][nt] = __builtin_amdgcn_mfma_f32_16x16x32_f16(af[mt], bf[nt], acc[mt][nt], 0, 0, 0);
        __syncthreads();
    }

    #pragma unroll
    for (int mt = 0; mt < 4; ++mt) {
        #pragma unroll
        for (int nt = 0; nt < 4; ++nt) {
            int n = n0 + wn*64 + nt*16 + ln;
            float bv = (bias0 ? bias0[n] : 0.f) + (bias1 ? bias1[n] : 0.f);
            #pragma unroll
            for (int r = 0; r < 4; ++r) {
                int m = m0 + wm*64 + mt*16 + hi*4 + r;
                Cout[(size_t)m*N + n] = (half_t)(acc[mt][nt][r] + bv);
            }
        }
    }
}

// ---------------- persistent bidirectional RNN layer (round 9) ----------------
// grid = 8 blocks (2 dir x 4 batch-groups) x 512 thr (8 waves, 2 per SIMD).
// Round-6 lesson: XOR swizzle costs VALU per access when the varying index bits overlap
// the XOR bits. Fix: K-MAJOR layouts so per-access terms are bits >=10 and the XOR
// (bits 4-5, within a 64B row) folds into a per-lane constant base -> zero VALU,
// immediate ds offsets, conflict-free (chunk c_phys = c_log ^ (row&3), bank-uniform).
//   wlds[kt 4][j 512][64B]  : read = wrdL + kt*32768 + mt*1024
//   hlds[buf 2][kk 16][b 16][64B]: read = hrdL + buf*16384 + kk*1024
// Exact fit 163840B = 160KiB -> h DOUBLE buffer -> ONE barrier/step (publishes writes
// AND proves prior reads done; lgkm-only, global stores stay fire-and-forget).
// Register split proven round 4: afrag[4][12]=192 regs (round-5: [4][16]=256 spills).
__global__ __launch_bounds__(512, 2)
void rnn_layer(const half_t* __restrict__ xp, half_t* __restrict__ outbuf,
               const half_t* __restrict__ whh16)
{
    extern __shared__ char smem[];
    char* wlds = smem;                 // [4][512][64B] W k-tail, k-major, chunk-XOR row&3
    char* hlds = smem + WTILE_BYTES;   // [2][16][16][64B] h dbuf, k-major, chunk-XOR b&3

    const int bid = blockIdx.x;
    const int dir = bid >> 2;
    const int bg  = bid & 3;
    const int w   = threadIdx.x >> 6;      // wave 0..7, owns j in [w*64, w*64+64)
    const int lane = threadIdx.x & 63;
    const int ln = lane & 15, hi = lane >> 4;

    const half_t* wbase = whh16 + (size_t)dir * HID * HID;

    // A fragments in regs: afrag[mt][kk] = W[w*64+mt*16+ln][kk*32+hi*8 ..+8], kk<12
    half8 afrag[4][KK_REG];
    #pragma unroll
    for (int mt = 0; mt < 4; ++mt) {
        #pragma unroll
        for (int kk = 0; kk < KK_REG; ++kk)
            afrag[mt][kk] = *(const half8*)(wbase + (size_t)(w*64 + mt*16 + ln)*HID + kk*32 + hi*8);
    }

    // stage W k-tail [384,512) k-major: row j, chunk c8 (16B) -> kt=c8>>2, chunk-XOR row&3
    for (int idx = threadIdx.x; idx < HID*16; idx += 512) {
        int row = idx >> 4, c8 = idx & 15;
        int off = (((c8 & 3) * 16) ^ ((row & 3) << 4));
        *(half8*)(wlds + (c8 >> 2)*32768 + row*64 + off) =
            *(const half8*)(wbase + (size_t)row*HID + K_REG + c8*8);
    }

    const int b  = bg*16 + ln;       // this lane's batch column
    const int jq = w*64 + hi*4;      // j quad base; mt adds 16

    const ptrdiff_t dstep = dir ? -(ptrdiff_t)(BATCH*2*HID) : (ptrdiff_t)(BATCH*2*HID);
    const int t0 = dir ? (SEQ-1) : 0;
    const size_t base0 = ((size_t)(t0*BATCH + b))*(2*HID) + (size_t)dir*HID + jq;
    const half_t* xb = xp + base0;
    half_t*       op = outbuf + base0;

    // per-lane LDS bases (XOR folded; per-access adders are bits>=10 -> immediate offsets)
    const int swz = ((hi*16) ^ ((ln & 3) << 4));
    const char* hrdL = hlds + ln*64 + swz;              // + buf*16384 + kk*1024
    const char* wrdL = wlds + (w*64 + ln)*64 + swz;     // + kt*32768 + mt*1024
    char*       hwrL = hlds + (w*2)*1024 + ln*64;       // + buf*16384 + (mt>>1)*1024 + woff[mt]
    // write offsets within 64B row: ((mt&1)*32 + hi*8) ^ ((ln&3)<<4)  (quad-level, bijective)
    int woff0 = ((0*32) + hi*8) ^ ((ln & 3) << 4);
    int woff1 = ((1*32) + hi*8) ^ ((ln & 3) << 4);

    // ---- step 0: h == 0 -> acc = xq(t0); no h reads, no MFMA ----
    half4 xq[4];
    #pragma unroll
    for (int mt = 0; mt < 4; ++mt) xq[mt] = *(const half4*)(xb + mt*16);
    xb += dstep;

    floatx4 acc[4];
    #pragma unroll
    for (int mt = 0; mt < 4; ++mt) {
        acc[mt][0] = (float)xq[mt][0]; acc[mt][1] = (float)xq[mt][1];
        acc[mt][2] = (float)xq[mt][2]; acc[mt][3] = (float)xq[mt][3];
    }
    // prefetch xq(t1)
    #pragma unroll
    for (int mt = 0; mt < 4; ++mt) xq[mt] = *(const half4*)(xb + mt*16);
    xb += dstep;

    {
        half4 hv[4];
        #pragma unroll
        for (int mt = 0; mt < 4; ++mt) {
            #pragma unroll
            for (int r = 0; r < 4; ++r)
                hv[mt][r] = (_Float16)fmaxf(acc[mt][r], 0.f);
            *(half4*)(hwrL + (mt >> 1)*1024 + ((mt & 1) ? woff1 : woff0)) = hv[mt];  // buf 0
            *(half4*)(op + mt*16) = hv[mt];
        }
        op += dstep;
    }
    // publish wlds staging + step-0 h writes
    asm volatile("s_waitcnt lgkmcnt(0)\n\ts_barrier" ::: "memory");

    for (int step = 1; step < SEQ; ++step) {
        const int rb = (step + 1) & 1;   // buffer holding h from previous step
        const int wb = step & 1;         // buffer to write h of this step
        const char* hrd = hrdL + rb*HBUF_BYTES;

        // seed acc from prefetched xq; issue next prefetch (lands under MFMA phase)
        #pragma unroll
        for (int mt = 0; mt < 4; ++mt) {
            acc[mt][0] = (float)xq[mt][0]; acc[mt][1] = (float)xq[mt][1];
            acc[mt][2] = (float)xq[mt][2]; acc[mt][3] = (float)xq[mt][3];
        }
        if (step + 1 < SEQ) {
            #pragma unroll
            for (int mt = 0; mt < 4; ++mt) xq[mt] = *(const half4*)(xb + mt*16);
        }
        xb += dstep;

        __builtin_amdgcn_s_setprio(1);
        // ---- k < 384: W in regs, h from LDS (2-deep paired pipeline, imm offsets) ----
        half8 c0 = *(const half8*)(hrd + 0*1024);
        half8 c1 = *(const half8*)(hrd + 1*1024);
        #pragma unroll
        for (int g = 0; g < 5; ++g) {
            half8 n0 = *(const half8*)(hrd + (2*g+2)*1024);
            half8 n1 = *(const half8*)(hrd + (2*g+3)*1024);
            #pragma unroll
            for (int mt = 0; mt < 4; ++mt)
                acc[mt] = __builtin_amdgcn_mfma_f32_16x16x32_f16(afrag[mt][2*g],   c0, acc[mt], 0, 0, 0);
            #pragma unroll
            for (int mt = 0; mt < 4; ++mt)
                acc[mt] = __builtin_amdgcn_mfma_f32_16x16x32_f16(afrag[mt][2*g+1], c1, acc[mt], 0, 0, 0);
            c0 = n0; c1 = n1;
        }
        #pragma unroll
        for (int mt = 0; mt < 4; ++mt)
            acc[mt] = __builtin_amdgcn_mfma_f32_16x16x32_f16(afrag[mt][10], c0, acc[mt], 0, 0, 0);
        #pragma unroll
        for (int mt = 0; mt < 4; ++mt)
            acc[mt] = __builtin_amdgcn_mfma_f32_16x16x32_f16(afrag[mt][11], c1, acc[mt], 0, 0, 0);

        // ---- k in [384,512): W k-tail + h from LDS (imm offsets) ----
        #pragma unroll
        for (int kt = 0; kt < 4; ++kt) {
            half8 ch = *(const half8*)(hrd + (KK_REG + kt)*1024);
            half8 w0 = *(const half8*)(wrdL + kt*32768 + 0*1024);
            half8 w1 = *(const half8*)(wrdL + kt*32768 + 1*1024);
            half8 w2 = *(const half8*)(wrdL + kt*32768 + 2*1024);
            half8 w3 = *(const half8*)(wrdL + kt*32768 + 3*1024);
            acc[0] = __builtin_amdgcn_mfma_f32_16x16x32_f16(w0, ch, acc[0], 0, 0, 0);
            acc[1] = __builtin_amdgcn_mfma_f32_16x16x32_f16(w1, ch, acc[1], 0, 0, 0);
            acc[2] = __builtin_amdgcn_mfma_f32_16x16x32_f16(w2, ch, acc[2], 0, 0, 0);
            acc[3] = __builtin_amdgcn_mfma_f32_16x16x32_f16(w3, ch, acc[3], 0, 0, 0);
        }
        __builtin_amdgcn_s_setprio(0);

        // ---- epilogue: hv = relu(acc) ----
        half4 hv[4];
        #pragma unroll
        for (int mt = 0; mt < 4; ++mt) {
            #pragma unroll
            for (int r = 0; r < 4; ++r)
                hv[mt][r] = (_Float16)fmaxf(acc[mt][r], 0.f);
        }

        if (step + 1 < SEQ) {
            char* hw = hwrL + wb*HBUF_BYTES;
            #pragma unroll
            for (int mt = 0; mt < 4; ++mt)
                *(half4*)(hw + (mt >> 1)*1024 + ((mt & 1) ? woff1 : woff0)) = hv[mt];
            // single barrier: publishes h(t+1) AND proves all reads of rb finished
            asm volatile("s_waitcnt lgkmcnt(0)\n\ts_barrier" ::: "memory");
        }

        // fire-and-forget global store (drained at kernel end)
        #pragma unroll
        for (int mt = 0; mt < 4; ++mt)
            *(half4*)(op + mt*16) = hv[mt];
        op += dstep;
    }
}

// ---------------- final FC: [16384,1024] x [18,1024]^T + b ----------------
__global__ __launch_bounds__(256)
void fc_kernel(const half_t* __restrict__ X, const half_t* __restrict__ W16,
               const float* __restrict__ bias, float* __restrict__ Y)
{
    __shared__ half8 Ws8[2304];   // 18*1024 half
    half_t* Ws = (half_t*)Ws8;
    for (int ch = threadIdx.x; ch < 2304; ch += 256)
        Ws8[ch] = *(const half8*)(W16 + (size_t)ch*8);
    __syncthreads();

    int wi = threadIdx.x >> 6, lane = threadIdx.x & 63;
    int m = blockIdx.x*4 + wi;
    const half_t* xr = X + (size_t)m*1024 + lane*16;
    half8 x0 = *(const half8*)xr;
    half8 x1 = *(const half8*)(xr + 8);
    float xa[16];
    #pragma unroll
    for (int i = 0; i < 8; ++i) { xa[i] = (float)x0[i]; xa[8+i] = (float)x1[i]; }

    for (int n = 0; n < NOUT; ++n) {
        const half_t* wr = Ws + n*1024 + lane*16;
        half8 w0 = *(const half8*)wr;
        half8 w1 = *(const half8*)(wr + 8);
        float s = 0.f;
        #pragma unroll
        for (int i = 0; i < 8; ++i) s += xa[i]*(float)w0[i] + xa[8+i]*(float)w1[i];
        #pragma unroll
        for (int off = 32; off > 0; off >>= 1) s += __shfl_down(s, off, 64);
        if (lane == 0) Y[(size_t)m*NOUT + n] = s + bias[n];
    }
}

// ---------------- launcher ----------------
extern "C" void kernel_launch(void* const* d_in, const int* in_sizes, int n_in,
                              void* d_out, int out_size, void* d_ws, size_t ws_size,
                              hipStream_t stream)
{
    const int*   text    = (const int*)  d_in[0];
    const float* emb     = (const float*)d_in[1];
    const float* emfc_w  = (const float*)d_in[2];
    const float* emfc_b  = (const float*)d_in[3];
    const float* w_ih0   = (const float*)d_in[4];
    const float* w_hh0   = (const float*)d_in[5];
    const float* b_ih0   = (const float*)d_in[6];
    const float* b_hh0   = (const float*)d_in[7];
    const float* w_ih1   = (const float*)d_in[8];
    const float* w_hh1   = (const float*)d_in[9];
    const float* b_ih1   = (const float*)d_in[10];
    const float* b_hh1   = (const float*)d_in[11];
    const float* fc_w    = (const float*)d_in[12];
    const float* fc_b    = (const float*)d_in[13];
    float* out = (float*)d_out;

    char* ws = (char*)d_ws;
    half_t* whh0_16 = (half_t*)(ws + O_WHH0_16);
    half_t* whh1_16 = (half_t*)(ws + O_WHH1_16);
    half_t* emfc16  = (half_t*)(ws + O_EMFC16);
    half_t* wih0    = (half_t*)(ws + O_WIH0);
    half_t* wih1    = (half_t*)(ws + O_WIH1);
    half_t* fc16    = (half_t*)(ws + O_FC16);
    half_t* pe      = (half_t*)(ws + O_PE);
    half_t* xp      = (half_t*)(ws + O_XP);
    half_t* out0    = (half_t*)(ws + O_OUT);
    half_t* out1    = (half_t*)(ws + O_OUT);   // aliased: out0 dead once xp1 GEMM done

    // one-time: allow full 160KB dynamic LDS for rnn_layer (host-side attr; capture-safe)
    static int attr_done = 0;
    if (!attr_done) {
        hipFuncSetAttribute((const void*)rnn_layer,
                            hipFuncAttributeMaxDynamicSharedMemorySize, LDS_BYTES);
        attr_done = 1;
    }

    // 1) weight conversions fp32->fp16
    cvt_f32f16<<<32,  256, 0, stream>>>(emfc_w, emfc16, 8192);
    cvt_f32f16<<<128, 256, 0, stream>>>(w_ih0,  wih0,  32768);
    cvt_f32f16<<<512, 256, 0, stream>>>(w_ih1,  wih1, 131072);
    cvt_f32f16<<<256, 256, 0, stream>>>(w_hh0,  whh0_16, 65536);
    cvt_f32f16<<<256, 256, 0, stream>>>(w_hh1,  whh1_16, 65536);
    cvt_f32f16<<<9,   256, 0, stream>>>(fc_w,   fc16,   2304);

    // 2) post_emb = gather(emb, text) @ emfc_w^T + emfc_b
    gemm_nt<true><<<dim3(M_TOT/128, EMB/128), 256, 0, stream>>>(
        nullptr, emb, text, emfc16, emfc_b, nullptr, pe, M_TOT, EMB, EMB);

    // 3) xp0 = post_emb @ w_ih0^T + (b_ih0 + b_hh0)
    gemm_nt<false><<<dim3(M_TOT/128, (2*HID)/128), 256, 0, stream>>>(
        pe, nullptr, nullptr, wih0, b_ih0, b_hh0, xp, M_TOT, 2*HID, EMB);

    // 4) layer0 recurrence (8 independent blocks x 8 waves)
    rnn_layer<<<8, 512, LDS_BYTES, stream>>>(xp, out0, whh0_16);

    // 5) xp1 = out0 @ w_ih1^T + (b_ih1 + b_hh1)
    gemm_nt<false><<<dim3(M_TOT/128, (2*HID)/128), 256, 0, stream>>>(
        out0, nullptr, nullptr, wih1, b_ih1, b_hh1, xp, M_TOT, 2*HID, 2*HID);

    // 6) layer1 recurrence
    rnn_layer<<<8, 512, LDS_BYTES, stream>>>(xp, out1, whh1_16);

    // 7) out = out1 @ fc_w^T + fc_b
    fc_kernel<<<M_TOT/4, 256, 0, stream>>>(out1, fc16, fc_b, out);
}

// Round 8
// 1365.151 us; speedup vs baseline: 1.9254x; 1.0303x over previous
//
#include <hip/hip_runtime.h>

typedef _Float16 half_t;
typedef _Float16 half4 __attribute__((ext_vector_type(4)));
typedef _Float16 half8 __attribute__((ext_vector_type(8)));
typedef float floatx4 __attribute__((ext_vector_type(4)));
typedef unsigned long long ull_t;

#define SEQ 256
#define BATCH 64
#define EMB 256
#define HID 512
#define NOUT 18
#define M_TOT (SEQ*BATCH)   // 16384

// rnn_layer geometry (round 10: round-7 + full-rank bank XOR)
#define KK_REG 12            // K-tiles (of 32) in registers: k < 384  (192 regs, proven round 4)
#define K_REG  (KK_REG*32)   // 384
#define WTILE_BYTES (4*HID*64)        // wlds [4 kt][512 j][64 B] = 131072
#define HBUF_BYTES  (16*16*64)        // one h buffer [16 kk][16 b][64 B] = 16384
#define LDS_BYTES (WTILE_BYTES + 2*HBUF_BYTES)  // 163840 = full 160 KiB

// ---------------- ws layout (bytes) ----------------
#define O_WHH0_16 0u          // 2*512*512 half = 1048576
#define O_WHH1_16 1048576u    // 1048576
#define O_EMFC16  2097152u    // 65536 half = 131072
#define O_WIH0    2228224u    // 1024*256 half = 524288
#define O_WIH1    2752512u    // 1024*1024 half = 2097152
#define O_FC16    4849664u    // 18*1024 half = 36864
#define O_PE      4886528u    // post_emb 16384*256 half = 8388608
#define O_XP      13275136u   // xp 16384*1024 half = 33554432 (shared by layer0/layer1)
#define O_OUT     46829568u   // 16384*1024 half (out0/out1 aliased; stream-ordered safe)
// total 80384000 bytes

// ---------------- fp32 -> fp16 convert (8 elems/thread) ----------------
__global__ void cvt_f32f16(const float* __restrict__ s, half_t* __restrict__ d, int n8) {
    int i = blockIdx.x * 256 + threadIdx.x;
    if (i < n8) {
        const float4* s4 = (const float4*)s;
        float4 a = s4[2*i], b = s4[2*i+1];
        half8 h;
        h[0]=(_Float16)a.x; h[1]=(_Float16)a.y; h[2]=(_Float16)a.z; h[3]=(_Float16)a.w;
        h[4]=(_Float16)b.x; h[5]=(_Float16)b.y; h[6]=(_Float16)b.z; h[7]=(_Float16)b.w;
        *(half8*)(d + (size_t)i*8) = h;
    }
}

// ---------------- generic NT GEMM: C[m,n] = sum_k A[m,k]*B[n,k] + bias ----------------
template<bool GATHER>
__global__ __launch_bounds__(256)
void gemm_nt(const half_t* __restrict__ A, const float* __restrict__ Atab,
             const int* __restrict__ gidx, const half_t* __restrict__ Bm,
             const float* __restrict__ bias0, const float* __restrict__ bias1,
             half_t* __restrict__ Cout, int M, int N, int K)
{
    __shared__ half8 As8[512];   // 128 x 32 half
    __shared__ half8 Bs8[512];
    half_t* As = (half_t*)As8;
    half_t* Bs = (half_t*)Bs8;

    const int tid  = threadIdx.x;
    const int lane = tid & 63, wid = tid >> 6;
    const int wm = wid >> 1, wn = wid & 1;
    const int ln = lane & 15, hi = lane >> 4;
    const int m0 = blockIdx.x * 128, n0 = blockIdx.y * 128;

    floatx4 acc[4][4] = {};
    const int kTiles = K >> 5;

    for (int kt = 0; kt < kTiles; ++kt) {
        if constexpr (GATHER) {
            int r = tid >> 1, q = tid & 1;
            int row = gidx[m0 + r];
            const float* src = Atab + (size_t)row * EMB + kt*32 + q*16;
            float4 f0 = *(const float4*)(src);
            float4 f1 = *(const float4*)(src + 4);
            float4 f2 = *(const float4*)(src + 8);
            float4 f3 = *(const float4*)(src + 12);
            half8 h0, h1;
            h0[0]=(_Float16)f0.x; h0[1]=(_Float16)f0.y; h0[2]=(_Float16)f0.z; h0[3]=(_Float16)f0.w;
            h0[4]=(_Float16)f1.x; h0[5]=(_Float16)f1.y; h0[6]=(_Float16)f1.z; h0[7]=(_Float16)f1.w;
            h1[0]=(_Float16)f2.x; h1[1]=(_Float16)f2.y; h1[2]=(_Float16)f2.z; h1[3]=(_Float16)f2.w;
            h1[4]=(_Float16)f3.x; h1[5]=(_Float16)f3.y; h1[6]=(_Float16)f3.z; h1[7]=(_Float16)f3.w;
            int c0 = 2*q, c1 = 2*q + 1;
            *(half8*)(As + r*32 + (((c0 + (r>>1)) & 3) * 8)) = h0;
            *(half8*)(As + r*32 + (((c1 + (r>>1)) & 3) * 8)) = h1;
        } else {
            #pragma unroll
            for (int ii = 0; ii < 2; ++ii) {
                int ch = tid + ii*256; int r = ch >> 2, c = ch & 3;
                half8 v = *(const half8*)(A + (size_t)(m0+r)*K + kt*32 + c*8);
                *(half8*)(As + r*32 + (((c + (r>>1)) & 3) * 8)) = v;
            }
        }
        #pragma unroll
        for (int ii = 0; ii < 2; ++ii) {
            int ch = tid + ii*256; int r = ch >> 2, c = ch & 3;
            half8 v = *(const half8*)(Bm + (size_t)(n0+r)*K + kt*32 + c*8);
            *(half8*)(Bs + r*32 + (((c + (r>>1)) & 3) * 8)) = v;
        }
        __syncthreads();

        half8 af[4], bf[4];
        #pragma unroll
        for (int mt = 0; mt < 4; ++mt) {
            int r = wm*64 + mt*16 + ln;
            af[mt] = *(const half8*)(As + r*32 + ((hi + (r>>1)) & 3) * 8);
        }
        #pragma unroll
        for (int nt = 0; nt < 4; ++nt) {
            int r = wn*64 + nt*16 + ln;
            bf[nt] = *(const half8*)(Bs + r*32 + ((hi + (r>>1)) & 3) * 8);
        }
        #pragma unroll
        for (int mt = 0; mt < 4; ++mt)
            #pragma unroll
            for (int nt = 0; nt < 4; ++nt)
                acc[mt][nt] = __builtin_amdgcn_mfma_f32_16x16x32_f16(af[mt], bf[nt], acc[mt][nt], 0, 0, 0);
        __syncthreads();
    }

    #pragma unroll
    for (int mt = 0; mt < 4; ++mt) {
        #pragma unroll
        for (int nt = 0; nt < 4; ++nt) {
            int n = n0 + wn*64 + nt*16 + ln;
            float bv = (bias0 ? bias0[n] : 0.f) + (bias1 ? bias1[n] : 0.f);
            #pragma unroll
            for (int r = 0; r < 4; ++r) {
                int m = m0 + wm*64 + mt*16 + hi*4 + r;
                Cout[(size_t)m*N + n] = (half_t)(acc[mt][nt][r] + bv);
            }
        }
    }
}

// ---------------- persistent bidirectional RNN layer (round 10) ----------------
// grid = 8 blocks (2 dir x 4 batch-groups) x 512 thr (8 waves, 2 per SIMD).
// Identical to round 7 except the chunk-XOR now has FULL row rank:
//   chunk_phys = chunk_log ^ (row&3) ^ ((row>>2)&3)
// Round-7 lesson: with 64B rows (16 banks), rows 4 apart alias the same bank quads;
// XOR by (row&3) alone left lanes {0,4,8,12} 4-way conflicted (measured 2.88M conflicts,
// ~1400 cy/step, LDS pipe 3450 cy > MFMA 2480 cy). Adding ^((row>>2)&3) makes any 8/16
// consecutive lanes cover all 32 banks <=2-way (2-way free, m136). XOR bits (4-5) remain
// disjoint from all per-access adders (kk*1024, kt*32768, mt*1024, buf*16384) -> still
// per-lane-constant bases + immediate ds offsets, zero extra VALU (round-6 lesson).
// Consistency: read row = b = ln; write chunk uses same (ln&3)^((ln>>2)&3); W staging
// row&3==ln&3 and (row>>2)&3==(ln>>2)&3 for all mt (mt*16 only touches bit 4).
__global__ __launch_bounds__(512, 2)
void rnn_layer(const half_t* __restrict__ xp, half_t* __restrict__ outbuf,
               const half_t* __restrict__ whh16)
{
    extern __shared__ char smem[];
    char* wlds = smem;                 // [4][512][64B] W k-tail, k-major, full-rank chunk XOR
    char* hlds = smem + WTILE_BYTES;   // [2][16][16][64B] h dbuf, k-major, full-rank chunk XOR

    const int bid = blockIdx.x;
    const int dir = bid >> 2;
    const int bg  = bid & 3;
    const int w   = threadIdx.x >> 6;      // wave 0..7, owns j in [w*64, w*64+64)
    const int lane = threadIdx.x & 63;
    const int ln = lane & 15, hi = lane >> 4;

    const half_t* wbase = whh16 + (size_t)dir * HID * HID;

    // A fragments in regs: afrag[mt][kk] = W[w*64+mt*16+ln][kk*32+hi*8 ..+8], kk<12
    half8 afrag[4][KK_REG];
    #pragma unroll
    for (int mt = 0; mt < 4; ++mt) {
        #pragma unroll
        for (int kk = 0; kk < KK_REG; ++kk)
            afrag[mt][kk] = *(const half8*)(wbase + (size_t)(w*64 + mt*16 + ln)*HID + kk*32 + hi*8);
    }

    // stage W k-tail [384,512) k-major: row j, 16B chunk c8 -> kt=c8>>2, full-rank chunk XOR
    for (int idx = threadIdx.x; idx < HID*16; idx += 512) {
        int row = idx >> 4, c8 = idx & 15;
        int off = ((((c8 & 3) ^ (row & 3) ^ ((row >> 2) & 3)) << 4));
        *(half8*)(wlds + (c8 >> 2)*32768 + row*64 + off) =
            *(const half8*)(wbase + (size_t)row*HID + K_REG + c8*8);
    }

    const int b  = bg*16 + ln;       // this lane's batch column
    const int jq = w*64 + hi*4;      // j quad base; mt adds 16

    const ptrdiff_t dstep = dir ? -(ptrdiff_t)(BATCH*2*HID) : (ptrdiff_t)(BATCH*2*HID);
    const int t0 = dir ? (SEQ-1) : 0;
    const size_t base0 = ((size_t)(t0*BATCH + b))*(2*HID) + (size_t)dir*HID + jq;
    const half_t* xb = xp + base0;
    half_t*       op = outbuf + base0;

    // per-lane LDS bases (full-rank XOR folded; per-access adders bits>=10 -> imm offsets)
    const int swz = ((hi ^ (ln & 3) ^ ((ln >> 2) & 3)) << 4);
    const char* hrdL = hlds + ln*64 + swz;              // + buf*16384 + kk*1024
    const char* wrdL = wlds + (w*64 + ln)*64 + swz;     // + kt*32768 + mt*1024
    char*       hwrL = hlds + (w*2)*1024 + ln*64;       // + buf*16384 + (mt>>1)*1024 + woff
    // write offsets within 64B row: chunk_log = (mt&1)*2 + (hi>>1), sub-off (hi&1)*8
    const int woff0 = ((((hi >> 1) ^ (ln & 3) ^ ((ln >> 2) & 3)) << 4)) + (hi & 1)*8;
    const int woff1 = woff0 ^ 32;

    // ---- step 0: h == 0 -> acc = xq(t0); no h reads, no MFMA ----
    half4 xq[4];
    #pragma unroll
    for (int mt = 0; mt < 4; ++mt) xq[mt] = *(const half4*)(xb + mt*16);
    xb += dstep;

    floatx4 acc[4];
    #pragma unroll
    for (int mt = 0; mt < 4; ++mt) {
        acc[mt][0] = (float)xq[mt][0]; acc[mt][1] = (float)xq[mt][1];
        acc[mt][2] = (float)xq[mt][2]; acc[mt][3] = (float)xq[mt][3];
    }
    // prefetch xq(t1)
    #pragma unroll
    for (int mt = 0; mt < 4; ++mt) xq[mt] = *(const half4*)(xb + mt*16);
    xb += dstep;

    {
        half4 hv[4];
        #pragma unroll
        for (int mt = 0; mt < 4; ++mt) {
            #pragma unroll
            for (int r = 0; r < 4; ++r)
                hv[mt][r] = (_Float16)fmaxf(acc[mt][r], 0.f);
            *(half4*)(hwrL + (mt >> 1)*1024 + ((mt & 1) ? woff1 : woff0)) = hv[mt];  // buf 0
            *(half4*)(op + mt*16) = hv[mt];
        }
        op += dstep;
    }
    // publish wlds staging + step-0 h writes
    asm volatile("s_waitcnt lgkmcnt(0)\n\ts_barrier" ::: "memory");

    for (int step = 1; step < SEQ; ++step) {
        const int rb = (step + 1) & 1;   // buffer holding h from previous step
        const int wb = step & 1;         // buffer to write h of this step
        const char* hrd = hrdL + rb*HBUF_BYTES;

        // seed acc from prefetched xq; issue next prefetch (lands under MFMA phase)
        #pragma unroll
        for (int mt = 0; mt < 4; ++mt) {
            acc[mt][0] = (float)xq[mt][0]; acc[mt][1] = (float)xq[mt][1];
            acc[mt][2] = (float)xq[mt][2]; acc[mt][3] = (float)xq[mt][3];
        }
        if (step + 1 < SEQ) {
            #pragma unroll
            for (int mt = 0; mt < 4; ++mt) xq[mt] = *(const half4*)(xb + mt*16);
        }
        xb += dstep;

        __builtin_amdgcn_s_setprio(1);
        // ---- k < 384: W in regs, h from LDS (2-deep paired pipeline, imm offsets) ----
        half8 c0 = *(const half8*)(hrd + 0*1024);
        half8 c1 = *(const half8*)(hrd + 1*1024);
        #pragma unroll
        for (int g = 0; g < 5; ++g) {
            half8 n0 = *(const half8*)(hrd + (2*g+2)*1024);
            half8 n1 = *(const half8*)(hrd + (2*g+3)*1024);
            #pragma unroll
            for (int mt = 0; mt < 4; ++mt)
                acc[mt] = __builtin_amdgcn_mfma_f32_16x16x32_f16(afrag[mt][2*g],   c0, acc[mt], 0, 0, 0);
            #pragma unroll
            for (int mt = 0; mt < 4; ++mt)
                acc[mt] = __builtin_amdgcn_mfma_f32_16x16x32_f16(afrag[mt][2*g+1], c1, acc[mt], 0, 0, 0);
            c0 = n0; c1 = n1;
        }
        #pragma unroll
        for (int mt = 0; mt < 4; ++mt)
            acc[mt] = __builtin_amdgcn_mfma_f32_16x16x32_f16(afrag[mt][10], c0, acc[mt], 0, 0, 0);
        #pragma unroll
        for (int mt = 0; mt < 4; ++mt)
            acc[mt] = __builtin_amdgcn_mfma_f32_16x16x32_f16(afrag[mt][11], c1, acc[mt], 0, 0, 0);

        // ---- k in [384,512): W k-tail + h from LDS (imm offsets) ----
        #pragma unroll
        for (int kt = 0; kt < 4; ++kt) {
            half8 ch = *(const half8*)(hrd + (KK_REG + kt)*1024);
            half8 w0 = *(const half8*)(wrdL + kt*32768 + 0*1024);
            half8 w1 = *(const half8*)(wrdL + kt*32768 + 1*1024);
            half8 w2 = *(const half8*)(wrdL + kt*32768 + 2*1024);
            half8 w3 = *(const half8*)(wrdL + kt*32768 + 3*1024);
            acc[0] = __builtin_amdgcn_mfma_f32_16x16x32_f16(w0, ch, acc[0], 0, 0, 0);
            acc[1] = __builtin_amdgcn_mfma_f32_16x16x32_f16(w1, ch, acc[1], 0, 0, 0);
            acc[2] = __builtin_amdgcn_mfma_f32_16x16x32_f16(w2, ch, acc[2], 0, 0, 0);
            acc[3] = __builtin_amdgcn_mfma_f32_16x16x32_f16(w3, ch, acc[3], 0, 0, 0);
        }
        __builtin_amdgcn_s_setprio(0);

        // ---- epilogue: hv = relu(acc) ----
        half4 hv[4];
        #pragma unroll
        for (int mt = 0; mt < 4; ++mt) {
            #pragma unroll
            for (int r = 0; r < 4; ++r)
                hv[mt][r] = (_Float16)fmaxf(acc[mt][r], 0.f);
        }

        if (step + 1 < SEQ) {
            char* hw = hwrL + wb*HBUF_BYTES;
            #pragma unroll
            for (int mt = 0; mt < 4; ++mt)
                *(half4*)(hw + (mt >> 1)*1024 + ((mt & 1) ? woff1 : woff0)) = hv[mt];
            // single barrier: publishes h(t+1) AND proves all reads of rb finished
            asm volatile("s_waitcnt lgkmcnt(0)\n\ts_barrier" ::: "memory");
        }

        // fire-and-forget global store (drained at kernel end)
        #pragma unroll
        for (int mt = 0; mt < 4; ++mt)
            *(half4*)(op + mt*16) = hv[mt];
        op += dstep;
    }
}

// ---------------- final FC: [16384,1024] x [18,1024]^T + b ----------------
__global__ __launch_bounds__(256)
void fc_kernel(const half_t* __restrict__ X, const half_t* __restrict__ W16,
               const float* __restrict__ bias, float* __restrict__ Y)
{
    __shared__ half8 Ws8[2304];   // 18*1024 half
    half_t* Ws = (half_t*)Ws8;
    for (int ch = threadIdx.x; ch < 2304; ch += 256)
        Ws8[ch] = *(const half8*)(W16 + (size_t)ch*8);
    __syncthreads();

    int wi = threadIdx.x >> 6, lane = threadIdx.x & 63;
    int m = blockIdx.x*4 + wi;
    const half_t* xr = X + (size_t)m*1024 + lane*16;
    half8 x0 = *(const half8*)xr;
    half8 x1 = *(const half8*)(xr + 8);
    float xa[16];
    #pragma unroll
    for (int i = 0; i < 8; ++i) { xa[i] = (float)x0[i]; xa[8+i] = (float)x1[i]; }

    for (int n = 0; n < NOUT; ++n) {
        const half_t* wr = Ws + n*1024 + lane*16;
        half8 w0 = *(const half8*)wr;
        half8 w1 = *(const half8*)(wr + 8);
        float s = 0.f;
        #pragma unroll
        for (int i = 0; i < 8; ++i) s += xa[i]*(float)w0[i] + xa[8+i]*(float)w1[i];
        #pragma unroll
        for (int off = 32; off > 0; off >>= 1) s += __shfl_down(s, off, 64);
        if (lane == 0) Y[(size_t)m*NOUT + n] = s + bias[n];
    }
}

// ---------------- launcher ----------------
extern "C" void kernel_launch(void* const* d_in, const int* in_sizes, int n_in,
                              void* d_out, int out_size, void* d_ws, size_t ws_size,
                              hipStream_t stream)
{
    const int*   text    = (const int*)  d_in[0];
    const float* emb     = (const float*)d_in[1];
    const float* emfc_w  = (const float*)d_in[2];
    const float* emfc_b  = (const float*)d_in[3];
    const float* w_ih0   = (const float*)d_in[4];
    const float* w_hh0   = (const float*)d_in[5];
    const float* b_ih0   = (const float*)d_in[6];
    const float* b_hh0   = (const float*)d_in[7];
    const float* w_ih1   = (const float*)d_in[8];
    const float* w_hh1   = (const float*)d_in[9];
    const float* b_ih1   = (const float*)d_in[10];
    const float* b_hh1   = (const float*)d_in[11];
    const float* fc_w    = (const float*)d_in[12];
    const float* fc_b    = (const float*)d_in[13];
    float* out = (float*)d_out;

    char* ws = (char*)d_ws;
    half_t* whh0_16 = (half_t*)(ws + O_WHH0_16);
    half_t* whh1_16 = (half_t*)(ws + O_WHH1_16);
    half_t* emfc16  = (half_t*)(ws + O_EMFC16);
    half_t* wih0    = (half_t*)(ws + O_WIH0);
    half_t* wih1    = (half_t*)(ws + O_WIH1);
    half_t* fc16    = (half_t*)(ws + O_FC16);
    half_t* pe      = (half_t*)(ws + O_PE);
    half_t* xp      = (half_t*)(ws + O_XP);
    half_t* out0    = (half_t*)(ws + O_OUT);
    half_t* out1    = (half_t*)(ws + O_OUT);   // aliased: out0 dead once xp1 GEMM done

    // one-time: allow full 160KB dynamic LDS for rnn_layer (host-side attr; capture-safe)
    static int attr_done = 0;
    if (!attr_done) {
        hipFuncSetAttribute((const void*)rnn_layer,
                            hipFuncAttributeMaxDynamicSharedMemorySize, LDS_BYTES);
        attr_done = 1;
    }

    // 1) weight conversions fp32->fp16
    cvt_f32f16<<<32,  256, 0, stream>>>(emfc_w, emfc16, 8192);
    cvt_f32f16<<<128, 256, 0, stream>>>(w_ih0,  wih0,  32768);
    cvt_f32f16<<<512, 256, 0, stream>>>(w_ih1,  wih1, 131072);
    cvt_f32f16<<<256, 256, 0, stream>>>(w_hh0,  whh0_16, 65536);
    cvt_f32f16<<<256, 256, 0, stream>>>(w_hh1,  whh1_16, 65536);
    cvt_f32f16<<<9,   256, 0, stream>>>(fc_w,   fc16,   2304);

    // 2) post_emb = gather(emb, text) @ emfc_w^T + emfc_b
    gemm_nt<true><<<dim3(M_TOT/128, EMB/128), 256, 0, stream>>>(
        nullptr, emb, text, emfc16, emfc_b, nullptr, pe, M_TOT, EMB, EMB);

    // 3) xp0 = post_emb @ w_ih0^T + (b_ih0 + b_hh0)
    gemm_nt<false><<<dim3(M_TOT/128, (2*HID)/128), 256, 0, stream>>>(
        pe, nullptr, nullptr, wih0, b_ih0, b_hh0, xp, M_TOT, 2*HID, EMB);

    // 4) layer0 recurrence (8 independent blocks x 8 waves)
    rnn_layer<<<8, 512, LDS_BYTES, stream>>>(xp, out0, whh0_16);

    // 5) xp1 = out0 @ w_ih1^T + (b_ih1 + b_hh1)
    gemm_nt<false><<<dim3(M_TOT/128, (2*HID)/128), 256, 0, stream>>>(
        out0, nullptr, nullptr, wih1, b_ih1, b_hh1, xp, M_TOT, 2*HID, 2*HID);

    // 6) layer1 recurrence
    rnn_layer<<<8, 512, LDS_BYTES, stream>>>(xp, out1, whh1_16);

    // 7) out = out1 @ fc_w^T + fc_b
    fc_kernel<<<M_TOT/4, 256, 0, stream>>>(out1, fc16, fc_b, out);
}

// Round 9
// 1172.511 us; speedup vs baseline: 2.2418x; 1.1643x over previous
//
#include <hip/hip_runtime.h>

typedef _Float16 half_t;
typedef _Float16 half4 __attribute__((ext_vector_type(4)));
typedef _Float16 half8 __attribute__((ext_vector_type(8)));
typedef float floatx4 __attribute__((ext_vector_type(4)));
typedef unsigned long long ull_t;

#define SEQ 256
#define BATCH 64
#define EMB 256
#define HID 512
#define NOUT 18
#define M_TOT (SEQ*BATCH)   // 16384

// rnn_layer geometry (round 11: r8 layout + scheduled W-tail + pre-barrier seed)
#define KK_REG 12            // K-tiles (of 32) in registers: k < 384  (192 regs, proven round 4)
#define K_REG  (KK_REG*32)   // 384
#define WTILE_BYTES (4*HID*64)        // wlds [4 kt][512 j][64 B] = 131072
#define HBUF_BYTES  (16*16*64)        // one h buffer [16 kk][16 b][64 B] = 16384
#define LDS_BYTES (WTILE_BYTES + 2*HBUF_BYTES)  // 163840 = full 160 KiB

// ---------------- ws layout (bytes) ----------------
#define O_WHH0_16 0u          // 2*512*512 half = 1048576
#define O_WHH1_16 1048576u    // 1048576
#define O_EMFC16  2097152u    // 65536 half = 131072
#define O_WIH0    2228224u    // 1024*256 half = 524288
#define O_WIH1    2752512u    // 1024*1024 half = 2097152
#define O_FC16    4849664u    // 18*1024 half = 36864
#define O_PE      4886528u    // post_emb 16384*256 half = 8388608
#define O_XP      13275136u   // xp 16384*1024 half = 33554432 (shared by layer0/layer1)
#define O_OUT     46829568u   // 16384*1024 half (out0/out1 aliased; stream-ordered safe)
// total 80384000 bytes

// ---------------- fp32 -> fp16 convert (8 elems/thread) ----------------
__global__ void cvt_f32f16(const float* __restrict__ s, half_t* __restrict__ d, int n8) {
    int i = blockIdx.x * 256 + threadIdx.x;
    if (i < n8) {
        const float4* s4 = (const float4*)s;
        float4 a = s4[2*i], b = s4[2*i+1];
        half8 h;
        h[0]=(_Float16)a.x; h[1]=(_Float16)a.y; h[2]=(_Float16)a.z; h[3]=(_Float16)a.w;
        h[4]=(_Float16)b.x; h[5]=(_Float16)b.y; h[6]=(_Float16)b.z; h[7]=(_Float16)b.w;
        *(half8*)(d + (size_t)i*8) = h;
    }
}

// ---------------- generic NT GEMM: C[m,n] = sum_k A[m,k]*B[n,k] + bias ----------------
template<bool GATHER>
__global__ __launch_bounds__(256)
void gemm_nt(const half_t* __restrict__ A, const float* __restrict__ Atab,
             const int* __restrict__ gidx, const half_t* __restrict__ Bm,
             const float* __restrict__ bias0, const float* __restrict__ bias1,
             half_t* __restrict__ Cout, int M, int N, int K)
{
    __shared__ half8 As8[512];   // 128 x 32 half
    __shared__ half8 Bs8[512];
    half_t* As = (half_t*)As8;
    half_t* Bs = (half_t*)Bs8;

    const int tid  = threadIdx.x;
    const int lane = tid & 63, wid = tid >> 6;
    const int wm = wid >> 1, wn = wid & 1;
    const int ln = lane & 15, hi = lane >> 4;
    const int m0 = blockIdx.x * 128, n0 = blockIdx.y * 128;

    floatx4 acc[4][4] = {};
    const int kTiles = K >> 5;

    for (int kt = 0; kt < kTiles; ++kt) {
        if constexpr (GATHER) {
            int r = tid >> 1, q = tid & 1;
            int row = gidx[m0 + r];
            const float* src = Atab + (size_t)row * EMB + kt*32 + q*16;
            float4 f0 = *(const float4*)(src);
            float4 f1 = *(const float4*)(src + 4);
            float4 f2 = *(const float4*)(src + 8);
            float4 f3 = *(const float4*)(src + 12);
            half8 h0, h1;
            h0[0]=(_Float16)f0.x; h0[1]=(_Float16)f0.y; h0[2]=(_Float16)f0.z; h0[3]=(_Float16)f0.w;
            h0[4]=(_Float16)f1.x; h0[5]=(_Float16)f1.y; h0[6]=(_Float16)f1.z; h0[7]=(_Float16)f1.w;
            h1[0]=(_Float16)f2.x; h1[1]=(_Float16)f2.y; h1[2]=(_Float16)f2.z; h1[3]=(_Float16)f2.w;
            h1[4]=(_Float16)f3.x; h1[5]=(_Float16)f3.y; h1[6]=(_Float16)f3.z; h1[7]=(_Float16)f3.w;
            int c0 = 2*q, c1 = 2*q + 1;
            *(half8*)(As + r*32 + (((c0 + (r>>1)) & 3) * 8)) = h0;
            *(half8*)(As + r*32 + (((c1 + (r>>1)) & 3) * 8)) = h1;
        } else {
            #pragma unroll
            for (int ii = 0; ii < 2; ++ii) {
                int ch = tid + ii*256; int r = ch >> 2, c = ch & 3;
                half8 v = *(const half8*)(A + (size_t)(m0+r)*K + kt*32 + c*8);
                *(half8*)(As + r*32 + (((c + (r>>1)) & 3) * 8)) = v;
            }
        }
        #pragma unroll
        for (int ii = 0; ii < 2; ++ii) {
            int ch = tid + ii*256; int r = ch >> 2, c = ch & 3;
            half8 v = *(const half8*)(Bm + (size_t)(n0+r)*K + kt*32 + c*8);
            *(half8*)(Bs + r*32 + (((c + (r>>1)) & 3) * 8)) = v;
        }
        __syncthreads();

        half8 af[4], bf[4];
        #pragma unroll
        for (int mt = 0; mt < 4; ++mt) {
            int r = wm*64 + mt*16 + ln;
            af[mt] = *(const half8*)(As + r*32 + ((hi + (r>>1)) & 3) * 8);
        }
        #pragma unroll
        for (int nt = 0; nt < 4; ++nt) {
            int r = wn*64 + nt*16 + ln;
            bf[nt] = *(const half8*)(Bs + r*32 + ((hi + (r>>1)) & 3) * 8);
        }
        #pragma unroll
        for (int mt = 0; mt < 4; ++mt)
            #pragma unroll
            for (int nt = 0; nt < 4; ++nt)
                acc[mt][nt] = __builtin_amdgcn_mfma_f32_16x16x32_f16(af[mt], bf[nt], acc[mt][nt], 0, 0, 0);
        __syncthreads();
    }

    #pragma unroll
    for (int mt = 0; mt < 4; ++mt) {
        #pragma unroll
        for (int nt = 0; nt < 4; ++nt) {
            int n = n0 + wn*64 + nt*16 + ln;
            float bv = (bias0 ? bias0[n] : 0.f) + (bias1 ? bias1[n] : 0.f);
            #pragma unroll
            for (int r = 0; r < 4; ++r) {
                int m = m0 + wm*64 + mt*16 + hi*4 + r;
                Cout[(size_t)m*N + n] = (half_t)(acc[mt][nt][r] + bv);
            }
        }
    }
}

// ---------------- persistent bidirectional RNN layer (round 11) ----------------
// grid = 8 blocks (2 dir x 4 batch-groups) x 512 thr (8 waves, 2 per SIMD).
// LAYOUT identical to round 8 (k-major, full-rank chunk XOR; conflicts at counter floor).
// SCHEDULE changes only (round-8 post-mortem: ~2300cy/step exposed latency):
//  (1) acc-seed (16 cvts) + next-xq load issue moved BEFORE the barrier -> post-barrier
//      region starts directly with LDS reads + MFMAs; xq regs dead during W-tail.
//  (2) W-tail pipelined 2-deep by hand with rotating A/B name sets: kt=0's ch+w reads
//      issued before the kk=10/11 MFMAs; each kt's reads interleaved into the previous
//      kt's MFMAs. Peak ~40 in-flight regs lands where c0/c1/n0/n1 (16) + xq (8) are
//      dead -> fits the 256-reg budget (round-5 lesson respected).
__global__ __launch_bounds__(512, 2)
void rnn_layer(const half_t* __restrict__ xp, half_t* __restrict__ outbuf,
               const half_t* __restrict__ whh16)
{
    extern __shared__ char smem[];
    char* wlds = smem;                 // [4][512][64B] W k-tail, k-major, full-rank chunk XOR
    char* hlds = smem + WTILE_BYTES;   // [2][16][16][64B] h dbuf, k-major, full-rank chunk XOR

    const int bid = blockIdx.x;
    const int dir = bid >> 2;
    const int bg  = bid & 3;
    const int w   = threadIdx.x >> 6;      // wave 0..7, owns j in [w*64, w*64+64)
    const int lane = threadIdx.x & 63;
    const int ln = lane & 15, hi = lane >> 4;

    const half_t* wbase = whh16 + (size_t)dir * HID * HID;

    // A fragments in regs: afrag[mt][kk] = W[w*64+mt*16+ln][kk*32+hi*8 ..+8], kk<12
    half8 afrag[4][KK_REG];
    #pragma unroll
    for (int mt = 0; mt < 4; ++mt) {
        #pragma unroll
        for (int kk = 0; kk < KK_REG; ++kk)
            afrag[mt][kk] = *(const half8*)(wbase + (size_t)(w*64 + mt*16 + ln)*HID + kk*32 + hi*8);
    }

    // stage W k-tail [384,512) k-major: row j, 16B chunk c8 -> kt=c8>>2, full-rank chunk XOR
    for (int idx = threadIdx.x; idx < HID*16; idx += 512) {
        int row = idx >> 4, c8 = idx & 15;
        int off = ((((c8 & 3) ^ (row & 3) ^ ((row >> 2) & 3)) << 4));
        *(half8*)(wlds + (c8 >> 2)*32768 + row*64 + off) =
            *(const half8*)(wbase + (size_t)row*HID + K_REG + c8*8);
    }

    const int b  = bg*16 + ln;       // this lane's batch column
    const int jq = w*64 + hi*4;      // j quad base; mt adds 16

    const ptrdiff_t dstep = dir ? -(ptrdiff_t)(BATCH*2*HID) : (ptrdiff_t)(BATCH*2*HID);
    const int t0 = dir ? (SEQ-1) : 0;
    const size_t base0 = ((size_t)(t0*BATCH + b))*(2*HID) + (size_t)dir*HID + jq;
    const half_t* xb = xp + base0;
    half_t*       op = outbuf + base0;

    // per-lane LDS bases (full-rank XOR folded; per-access adders bits>=10 -> imm offsets)
    const int swz = ((hi ^ (ln & 3) ^ ((ln >> 2) & 3)) << 4);
    const char* hrdL = hlds + ln*64 + swz;              // + buf*16384 + kk*1024
    const char* wrdL = wlds + (w*64 + ln)*64 + swz;     // + kt*32768 + mt*1024
    char*       hwrL = hlds + (w*2)*1024 + ln*64;       // + buf*16384 + (mt>>1)*1024 + woff
    const int woff0 = ((((hi >> 1) ^ (ln & 3) ^ ((ln >> 2) & 3)) << 4)) + (hi & 1)*8;
    const int woff1 = woff0 ^ 32;

    // ---- step 0: h == 0 -> acc = xq(t0); no h reads, no MFMA ----
    half4 xq[4];
    #pragma unroll
    for (int mt = 0; mt < 4; ++mt) xq[mt] = *(const half4*)(xb + mt*16);
    xb += dstep;

    floatx4 acc[4];
    #pragma unroll
    for (int mt = 0; mt < 4; ++mt) {
        acc[mt][0] = (float)xq[mt][0]; acc[mt][1] = (float)xq[mt][1];
        acc[mt][2] = (float)xq[mt][2]; acc[mt][3] = (float)xq[mt][3];
    }
    // prefetch xq(t1)
    #pragma unroll
    for (int mt = 0; mt < 4; ++mt) xq[mt] = *(const half4*)(xb + mt*16);
    xb += dstep;

    {
        half4 hv[4];
        #pragma unroll
        for (int mt = 0; mt < 4; ++mt) {
            #pragma unroll
            for (int r = 0; r < 4; ++r)
                hv[mt][r] = (_Float16)fmaxf(acc[mt][r], 0.f);
            *(half4*)(hwrL + (mt >> 1)*1024 + ((mt & 1) ? woff1 : woff0)) = hv[mt];  // buf 0
            *(half4*)(op + mt*16) = hv[mt];
        }
        op += dstep;
    }
    // pre-barrier seed for step 1 (xq = xp(t1)); issue xq(t2) loads
    #pragma unroll
    for (int mt = 0; mt < 4; ++mt) {
        acc[mt][0] = (float)xq[mt][0]; acc[mt][1] = (float)xq[mt][1];
        acc[mt][2] = (float)xq[mt][2]; acc[mt][3] = (float)xq[mt][3];
    }
    #pragma unroll
    for (int mt = 0; mt < 4; ++mt) xq[mt] = *(const half4*)(xb + mt*16);
    xb += dstep;
    // publish wlds staging + step-0 h writes
    asm volatile("s_waitcnt lgkmcnt(0)\n\ts_barrier" ::: "memory");

    for (int step = 1; step < SEQ; ++step) {
        const int rb = (step + 1) & 1;   // buffer holding h from previous step
        const int wb = step & 1;         // buffer to write h of this step
        const char* hrd = hrdL + rb*HBUF_BYTES;

        // acc already seeded pre-barrier; post-barrier region starts with reads+MFMAs
        __builtin_amdgcn_s_setprio(1);
        // ---- k < 384: W in regs, h from LDS (2-deep paired pipeline, imm offsets) ----
        half8 c0 = *(const half8*)(hrd + 0*1024);
        half8 c1 = *(const half8*)(hrd + 1*1024);
        #pragma unroll
        for (int g = 0; g < 5; ++g) {
            half8 n0 = *(const half8*)(hrd + (2*g+2)*1024);
            half8 n1 = *(const half8*)(hrd + (2*g+3)*1024);
            #pragma unroll
            for (int mt = 0; mt < 4; ++mt)
                acc[mt] = __builtin_amdgcn_mfma_f32_16x16x32_f16(afrag[mt][2*g],   c0, acc[mt], 0, 0, 0);
            #pragma unroll
            for (int mt = 0; mt < 4; ++mt)
                acc[mt] = __builtin_amdgcn_mfma_f32_16x16x32_f16(afrag[mt][2*g+1], c1, acc[mt], 0, 0, 0);
            c0 = n0; c1 = n1;
        }
        // preload W-tail kt=0 group (ch + 4 w) in the shadow of the kk=10/11 MFMAs
        half8 chA = *(const half8*)(hrd + 12*1024);
        half8 wA0 = *(const half8*)(wrdL + 0*32768 + 0*1024);
        half8 wA1 = *(const half8*)(wrdL + 0*32768 + 1*1024);
        half8 wA2 = *(const half8*)(wrdL + 0*32768 + 2*1024);
        half8 wA3 = *(const half8*)(wrdL + 0*32768 + 3*1024);
        #pragma unroll
        for (int mt = 0; mt < 4; ++mt)
            acc[mt] = __builtin_amdgcn_mfma_f32_16x16x32_f16(afrag[mt][10], c0, acc[mt], 0, 0, 0);
        #pragma unroll
        for (int mt = 0; mt < 4; ++mt)
            acc[mt] = __builtin_amdgcn_mfma_f32_16x16x32_f16(afrag[mt][11], c1, acc[mt], 0, 0, 0);

        // ---- k in [384,512): hand-pipelined 2-deep, rotating A/B name sets ----
        // kt=0 (A), prefetch kt=1 (B) interleaved
        half8 chB = *(const half8*)(hrd + 13*1024);
        half8 wB0 = *(const half8*)(wrdL + 1*32768 + 0*1024);
        half8 wB1 = *(const half8*)(wrdL + 1*32768 + 1*1024);
        acc[0] = __builtin_amdgcn_mfma_f32_16x16x32_f16(wA0, chA, acc[0], 0, 0, 0);
        acc[1] = __builtin_amdgcn_mfma_f32_16x16x32_f16(wA1, chA, acc[1], 0, 0, 0);
        half8 wB2 = *(const half8*)(wrdL + 1*32768 + 2*1024);
        half8 wB3 = *(const half8*)(wrdL + 1*32768 + 3*1024);
        acc[2] = __builtin_amdgcn_mfma_f32_16x16x32_f16(wA2, chA, acc[2], 0, 0, 0);
        acc[3] = __builtin_amdgcn_mfma_f32_16x16x32_f16(wA3, chA, acc[3], 0, 0, 0);
        // kt=1 (B), prefetch kt=2 (A)
        chA = *(const half8*)(hrd + 14*1024);
        wA0 = *(const half8*)(wrdL + 2*32768 + 0*1024);
        wA1 = *(const half8*)(wrdL + 2*32768 + 1*1024);
        acc[0] = __builtin_amdgcn_mfma_f32_16x16x32_f16(wB0, chB, acc[0], 0, 0, 0);
        acc[1] = __builtin_amdgcn_mfma_f32_16x16x32_f16(wB1, chB, acc[1], 0, 0, 0);
        wA2 = *(const half8*)(wrdL + 2*32768 + 2*1024);
        wA3 = *(const half8*)(wrdL + 2*32768 + 3*1024);
        acc[2] = __builtin_amdgcn_mfma_f32_16x16x32_f16(wB2, chB, acc[2], 0, 0, 0);
        acc[3] = __builtin_amdgcn_mfma_f32_16x16x32_f16(wB3, chB, acc[3], 0, 0, 0);
        // kt=2 (A), prefetch kt=3 (B)
        chB = *(const half8*)(hrd + 15*1024);
        wB0 = *(const half8*)(wrdL + 3*32768 + 0*1024);
        wB1 = *(const half8*)(wrdL + 3*32768 + 1*1024);
        acc[0] = __builtin_amdgcn_mfma_f32_16x16x32_f16(wA0, chA, acc[0], 0, 0, 0);
        acc[1] = __builtin_amdgcn_mfma_f32_16x16x32_f16(wA1, chA, acc[1], 0, 0, 0);
        wB2 = *(const half8*)(wrdL + 3*32768 + 2*1024);
        wB3 = *(const half8*)(wrdL + 3*32768 + 3*1024);
        acc[2] = __builtin_amdgcn_mfma_f32_16x16x32_f16(wA2, chA, acc[2], 0, 0, 0);
        acc[3] = __builtin_amdgcn_mfma_f32_16x16x32_f16(wA3, chA, acc[3], 0, 0, 0);
        // kt=3 (B)
        acc[0] = __builtin_amdgcn_mfma_f32_16x16x32_f16(wB0, chB, acc[0], 0, 0, 0);
        acc[1] = __builtin_amdgcn_mfma_f32_16x16x32_f16(wB1, chB, acc[1], 0, 0, 0);
        acc[2] = __builtin_amdgcn_mfma_f32_16x16x32_f16(wB2, chB, acc[2], 0, 0, 0);
        acc[3] = __builtin_amdgcn_mfma_f32_16x16x32_f16(wB3, chB, acc[3], 0, 0, 0);
        __builtin_amdgcn_s_setprio(0);

        // ---- epilogue: hv = relu(acc); h-write ----
        half4 hv[4];
        #pragma unroll
        for (int mt = 0; mt < 4; ++mt) {
            #pragma unroll
            for (int r = 0; r < 4; ++r)
                hv[mt][r] = (_Float16)fmaxf(acc[mt][r], 0.f);
        }

        if (step + 1 < SEQ) {
            char* hw = hwrL + wb*HBUF_BYTES;
            #pragma unroll
            for (int mt = 0; mt < 4; ++mt)
                *(half4*)(hw + (mt >> 1)*1024 + ((mt & 1) ? woff1 : woff0)) = hv[mt];
            // pre-barrier: seed acc for step+1 from xq=xp(t(step+1)); issue xq(t(step+2))
            #pragma unroll
            for (int mt = 0; mt < 4; ++mt) {
                acc[mt][0] = (float)xq[mt][0]; acc[mt][1] = (float)xq[mt][1];
                acc[mt][2] = (float)xq[mt][2]; acc[mt][3] = (float)xq[mt][3];
            }
            if (step + 2 < SEQ) {
                #pragma unroll
                for (int mt = 0; mt < 4; ++mt) xq[mt] = *(const half4*)(xb + mt*16);
            }
            xb += dstep;
            // single barrier: publishes h(t+1) AND proves all reads of rb finished
            asm volatile("s_waitcnt lgkmcnt(0)\n\ts_barrier" ::: "memory");
        }

        // fire-and-forget global store (drained at kernel end)
        #pragma unroll
        for (int mt = 0; mt < 4; ++mt)
            *(half4*)(op + mt*16) = hv[mt];
        op += dstep;
    }
}

// ---------------- final FC: [16384,1024] x [18,1024]^T + b ----------------
__global__ __launch_bounds__(256)
void fc_kernel(const half_t* __restrict__ X, const half_t* __restrict__ W16,
               const float* __restrict__ bias, float* __restrict__ Y)
{
    __shared__ half8 Ws8[2304];   // 18*1024 half
    half_t* Ws = (half_t*)Ws8;
    for (int ch = threadIdx.x; ch < 2304; ch += 256)
        Ws8[ch] = *(const half8*)(W16 + (size_t)ch*8);
    __syncthreads();

    int wi = threadIdx.x >> 6, lane = threadIdx.x & 63;
    int m = blockIdx.x*4 + wi;
    const half_t* xr = X + (size_t)m*1024 + lane*16;
    half8 x0 = *(const half8*)xr;
    half8 x1 = *(const half8*)(xr + 8);
    float xa[16];
    #pragma unroll
    for (int i = 0; i < 8; ++i) { xa[i] = (float)x0[i]; xa[8+i] = (float)x1[i]; }

    for (int n = 0; n < NOUT; ++n) {
        const half_t* wr = Ws + n*1024 + lane*16;
        half8 w0 = *(const half8*)wr;
        half8 w1 = *(const half8*)(wr + 8);
        float s = 0.f;
        #pragma unroll
        for (int i = 0; i < 8; ++i) s += xa[i]*(float)w0[i] + xa[8+i]*(float)w1[i];
        #pragma unroll
        for (int off = 32; off > 0; off >>= 1) s += __shfl_down(s, off, 64);
        if (lane == 0) Y[(size_t)m*NOUT + n] = s + bias[n];
    }
}

// ---------------- launcher ----------------
extern "C" void kernel_launch(void* const* d_in, const int* in_sizes, int n_in,
                              void* d_out, int out_size, void* d_ws, size_t ws_size,
                              hipStream_t stream)
{
    const int*   text    = (const int*)  d_in[0];
    const float* emb     = (const float*)d_in[1];
    const float* emfc_w  = (const float*)d_in[2];
    const float* emfc_b  = (const float*)d_in[3];
    const float* w_ih0   = (const float*)d_in[4];
    const float* w_hh0   = (const float*)d_in[5];
    const float* b_ih0   = (const float*)d_in[6];
    const float* b_hh0   = (const float*)d_in[7];
    const float* w_ih1   = (const float*)d_in[8];
    const float* w_hh1   = (const float*)d_in[9];
    const float* b_ih1   = (const float*)d_in[10];
    const float* b_hh1   = (const float*)d_in[11];
    const float* fc_w    = (const float*)d_in[12];
    const float* fc_b    = (const float*)d_in[13];
    float* out = (float*)d_out;

    char* ws = (char*)d_ws;
    half_t* whh0_16 = (half_t*)(ws + O_WHH0_16);
    half_t* whh1_16 = (half_t*)(ws + O_WHH1_16);
    half_t* emfc16  = (half_t*)(ws + O_EMFC16);
    half_t* wih0    = (half_t*)(ws + O_WIH0);
    half_t* wih1    = (half_t*)(ws + O_WIH1);
    half_t* fc16    = (half_t*)(ws + O_FC16);
    half_t* pe      = (half_t*)(ws + O_PE);
    half_t* xp      = (half_t*)(ws + O_XP);
    half_t* out0    = (half_t*)(ws + O_OUT);
    half_t* out1    = (half_t*)(ws + O_OUT);   // aliased: out0 dead once xp1 GEMM done

    // one-time: allow full 160KB dynamic LDS for rnn_layer (host-side attr; capture-safe)
    static int attr_done = 0;
    if (!attr_done) {
        hipFuncSetAttribute((const void*)rnn_layer,
                            hipFuncAttributeMaxDynamicSharedMemorySize, LDS_BYTES);
        attr_done = 1;
    }

    // 1) weight conversions fp32->fp16
    cvt_f32f16<<<32,  256, 0, stream>>>(emfc_w, emfc16, 8192);
    cvt_f32f16<<<128, 256, 0, stream>>>(w_ih0,  wih0,  32768);
    cvt_f32f16<<<512, 256, 0, stream>>>(w_ih1,  wih1, 131072);
    cvt_f32f16<<<256, 256, 0, stream>>>(w_hh0,  whh0_16, 65536);
    cvt_f32f16<<<256, 256, 0, stream>>>(w_hh1,  whh1_16, 65536);
    cvt_f32f16<<<9,   256, 0, stream>>>(fc_w,   fc16,   2304);

    // 2) post_emb = gather(emb, text) @ emfc_w^T + emfc_b
    gemm_nt<true><<<dim3(M_TOT/128, EMB/128), 256, 0, stream>>>(
        nullptr, emb, text, emfc16, emfc_b, nullptr, pe, M_TOT, EMB, EMB);

    // 3) xp0 = post_emb @ w_ih0^T + (b_ih0 + b_hh0)
    gemm_nt<false><<<dim3(M_TOT/128, (2*HID)/128), 256, 0, stream>>>(
        pe, nullptr, nullptr, wih0, b_ih0, b_hh0, xp, M_TOT, 2*HID, EMB);

    // 4) layer0 recurrence (8 independent blocks x 8 waves)
    rnn_layer<<<8, 512, LDS_BYTES, stream>>>(xp, out0, whh0_16);

    // 5) xp1 = out0 @ w_ih1^T + (b_ih1 + b_hh1)
    gemm_nt<false><<<dim3(M_TOT/128, (2*HID)/128), 256, 0, stream>>>(
        out0, nullptr, nullptr, wih1, b_ih1, b_hh1, xp, M_TOT, 2*HID, 2*HID);

    // 6) layer1 recurrence
    rnn_layer<<<8, 512, LDS_BYTES, stream>>>(xp, out1, whh1_16);

    // 7) out = out1 @ fc_w^T + fc_b
    fc_kernel<<<M_TOT/4, 256, 0, stream>>>(out1, fc16, fc_b, out);
}

// Round 10
// 1163.821 us; speedup vs baseline: 2.2585x; 1.0075x over previous
//
#include <hip/hip_runtime.h>

typedef _Float16 half_t;
typedef _Float16 half4 __attribute__((ext_vector_type(4)));
typedef _Float16 half8 __attribute__((ext_vector_type(8)));
typedef float floatx4 __attribute__((ext_vector_type(4)));
typedef unsigned long long ull_t;

typedef __attribute__((address_space(1))) const void gv1_t;
typedef __attribute__((address_space(3))) void lv3_t;

#define SEQ 256
#define BATCH 64
#define EMB 256
#define HID 512
#define NOUT 18
#define M_TOT (SEQ*BATCH)   // 16384

// rnn_layer geometry (round 10 layout, unchanged from round 9)
#define KK_REG 12            // K-tiles (of 32) in registers: k < 384
#define K_REG  (KK_REG*32)   // 384
#define WTILE_BYTES (4*HID*64)        // wlds [4 kt][512 j][64 B] = 131072
#define HBUF_BYTES  (16*16*64)        // one h buffer [16 kk][16 b][64 B] = 16384
#define LDS_BYTES (WTILE_BYTES + 2*HBUF_BYTES)  // 163840 = full 160 KiB

// ---------------- ws layout (bytes) ----------------
#define O_WHH0_16 0u          // 2*512*512 half = 1048576
#define O_WHH1_16 1048576u    // 1048576
#define O_EMFC16  2097152u    // 65536 half = 131072
#define O_WIH0    2228224u    // 1024*256 half = 524288
#define O_WIH1    2752512u    // 1024*1024 half = 2097152
#define O_FC16    4849664u    // 18*1024 half = 36864
#define O_PE      4886528u    // post_emb 16384*256 half = 8388608
#define O_XP      13275136u   // xp 16384*1024 half = 33554432 (shared by layer0/layer1)
#define O_OUT     46829568u   // 16384*1024 half (out0/out1 aliased; stream-ordered safe)
// total 80384000 bytes

// ---------------- fused fp32 -> fp16 convert: 6 segments, one launch ----------------
struct CvtJobs { const float* s[6]; half_t* d[6]; int n8[6]; };

__global__ void cvt6(CvtJobs j) {
    const int seg = blockIdx.y;
    const float* s = j.s[seg];
    half_t* d = j.d[seg];
    const int n8 = j.n8[seg];
    for (int i = blockIdx.x*256 + threadIdx.x; i < n8; i += gridDim.x*256) {
        const float4* s4 = (const float4*)s;
        float4 a = s4[2*i], b = s4[2*i+1];
        half8 h;
        h[0]=(_Float16)a.x; h[1]=(_Float16)a.y; h[2]=(_Float16)a.z; h[3]=(_Float16)a.w;
        h[4]=(_Float16)b.x; h[5]=(_Float16)b.y; h[6]=(_Float16)b.z; h[7]=(_Float16)b.w;
        *(half8*)(d + (size_t)i*8) = h;
    }
}

// ---------------- generic NT GEMM: C[m,n] = sum_k A[m,k]*B[n,k] + bias ----------------
// BM=128 BN=128 BK=32, 256 threads (4 waves 2x2), fp16 MFMA 16x16x32, fp16 out.
// Round-10: GATHER=false path stages A and B via global_load_lds (width 16).
// LDS destination is LINEAR (chunk p at byte 16p); the frag-read swizzle
// (phys slot = (c + (r>>1))&3) is preserved by pre-swizzling the GLOBAL source:
// for linear chunk p -> row r=p>>2, slot s=p&3, logical chunk c=(s-(r>>1))&3.
// GATHER=true path untouched (reg-staged gather + cvt).
template<bool GATHER>
__global__ __launch_bounds__(256)
void gemm_nt(const half_t* __restrict__ A, const float* __restrict__ Atab,
             const int* __restrict__ gidx, const half_t* __restrict__ Bm,
             const float* __restrict__ bias0, const float* __restrict__ bias1,
             half_t* __restrict__ Cout, int M, int N, int K)
{
    __shared__ half8 As8[512];   // 128 x 32 half
    __shared__ half8 Bs8[512];
    half_t* As = (half_t*)As8;
    half_t* Bs = (half_t*)Bs8;

    const int tid  = threadIdx.x;
    const int lane = tid & 63, wid = tid >> 6;
    const int wm = wid >> 1, wn = wid & 1;
    const int ln = lane & 15, hi = lane >> 4;
    const int m0 = blockIdx.x * 128, n0 = blockIdx.y * 128;

    floatx4 acc[4][4] = {};
    const int kTiles = K >> 5;

    // staging addresses for the gload_lds path (GATHER=false)
    const int p0 = tid, p1 = tid + 256;
    const int r0 = p0 >> 2, c0i = ((p0 & 3) - (r0 >> 1)) & 3;
    const int r1 = p1 >> 2, c1i = ((p1 & 3) - (r1 >> 1)) & 3;
    const int wbase0 = (tid & 192);         // linear chunk base for instr 0 (wave-uniform)
    const int wbase1 = (tid & 192) + 256;   // instr 1

    const half_t* gA0; const half_t* gA1;
    const half_t* gB0 = Bm + (size_t)(n0 + r0)*K + c0i*8;
    const half_t* gB1 = Bm + (size_t)(n0 + r1)*K + c1i*8;
    half_t* ldsA0 = As + (size_t)wbase0*8;
    half_t* ldsA1 = As + (size_t)wbase1*8;
    half_t* ldsB0 = Bs + (size_t)wbase0*8;
    half_t* ldsB1 = Bs + (size_t)wbase1*8;
    if constexpr (!GATHER) {
        gA0 = A + (size_t)(m0 + r0)*K + c0i*8;
        gA1 = A + (size_t)(m0 + r1)*K + c1i*8;
    }

    for (int kt = 0; kt < kTiles; ++kt) {
        if constexpr (GATHER) {
            // ---- old reg-staged path (A gathered + cvt, B via ds_write) ----
            {
                int r = tid >> 1, q = tid & 1;
                int row = gidx[m0 + r];
                const float* src = Atab + (size_t)row * EMB + kt*32 + q*16;
                float4 f0 = *(const float4*)(src);
                float4 f1 = *(const float4*)(src + 4);
                float4 f2 = *(const float4*)(src + 8);
                float4 f3 = *(const float4*)(src + 12);
                half8 h0, h1;
                h0[0]=(_Float16)f0.x; h0[1]=(_Float16)f0.y; h0[2]=(_Float16)f0.z; h0[3]=(_Float16)f0.w;
                h0[4]=(_Float16)f1.x; h0[5]=(_Float16)f1.y; h0[6]=(_Float16)f1.z; h0[7]=(_Float16)f1.w;
                h1[0]=(_Float16)f2.x; h1[1]=(_Float16)f2.y; h1[2]=(_Float16)f2.z; h1[3]=(_Float16)f2.w;
                h1[4]=(_Float16)f3.x; h1[5]=(_Float16)f3.y; h1[6]=(_Float16)f3.z; h1[7]=(_Float16)f3.w;
                int c0 = 2*q, c1 = 2*q + 1;
                *(half8*)(As + r*32 + (((c0 + (r>>1)) & 3) * 8)) = h0;
                *(half8*)(As + r*32 + (((c1 + (r>>1)) & 3) * 8)) = h1;
            }
            #pragma unroll
            for (int ii = 0; ii < 2; ++ii) {
                int ch = tid + ii*256; int r = ch >> 2, c = ch & 3;
                half8 v = *(const half8*)(Bm + (size_t)(n0+r)*K + kt*32 + c*8);
                *(half8*)(Bs + r*32 + (((c + (r>>1)) & 3) * 8)) = v;
            }
        } else {
            // ---- async global->LDS staging, 16B/lane, linear LDS dest ----
            __builtin_amdgcn_global_load_lds((gv1_t*)gA0, (lv3_t*)ldsA0, 16, 0, 0);
            __builtin_amdgcn_global_load_lds((gv1_t*)gA1, (lv3_t*)ldsA1, 16, 0, 0);
            __builtin_amdgcn_global_load_lds((gv1_t*)gB0, (lv3_t*)ldsB0, 16, 0, 0);
            __builtin_amdgcn_global_load_lds((gv1_t*)gB1, (lv3_t*)ldsB1, 16, 0, 0);
            gA0 += 32; gA1 += 32; gB0 += 32; gB1 += 32;
        }
        __syncthreads();   // drains vmcnt (gload_lds) + lgkmcnt (ds_write)

        half8 af[4], bf[4];
        #pragma unroll
        for (int mt = 0; mt < 4; ++mt) {
            int r = wm*64 + mt*16 + ln;
            af[mt] = *(const half8*)(As + r*32 + ((hi + (r>>1)) & 3) * 8);
        }
        #pragma unroll
        for (int nt = 0; nt < 4; ++nt) {
            int r = wn*64 + nt*16 + ln;
            bf[nt] = *(const half8*)(Bs + r*32 + ((hi + (r>>1)) & 3) * 8);
        }
        #pragma unroll
        for (int mt = 0; mt < 4; ++mt)
            #pragma unroll
            for (int nt = 0; nt < 4; ++nt)
                acc[mt][nt] = __builtin_amdgcn_mfma_f32_16x16x32_f16(af[mt], bf[nt], acc[mt][nt], 0, 0, 0);
        __syncthreads();
    }

    #pragma unroll
    for (int mt = 0; mt < 4; ++mt) {
        #pragma unroll
        for (int nt = 0; nt < 4; ++nt) {
            int n = n0 + wn*64 + nt*16 + ln;
            float bv = (bias0 ? bias0[n] : 0.f) + (bias1 ? bias1[n] : 0.f);
            #pragma unroll
            for (int r = 0; r < 4; ++r) {
                int m = m0 + wm*64 + mt*16 + hi*4 + r;
                Cout[(size_t)m*N + n] = (half_t)(acc[mt][nt][r] + bv);
            }
        }
    }
}

// ---------------- persistent bidirectional RNN layer (round 9, UNCHANGED) ----------------
// grid = 8 blocks (2 dir x 4 batch-groups) x 512 thr (8 waves, 2 per SIMD).
// k-major LDS, full-rank chunk XOR, 1 barrier/step, pre-barrier acc seed,
// hand-pipelined W-tail. Verified 464 us/dispatch (round 9).
__global__ __launch_bounds__(512, 2)
void rnn_layer(const half_t* __restrict__ xp, half_t* __restrict__ outbuf,
               const half_t* __restrict__ whh16)
{
    extern __shared__ char smem[];
    char* wlds = smem;                 // [4][512][64B] W k-tail, k-major, full-rank chunk XOR
    char* hlds = smem + WTILE_BYTES;   // [2][16][16][64B] h dbuf, k-major, full-rank chunk XOR

    const int bid = blockIdx.x;
    const int dir = bid >> 2;
    const int bg  = bid & 3;
    const int w   = threadIdx.x >> 6;      // wave 0..7, owns j in [w*64, w*64+64)
    const int lane = threadIdx.x & 63;
    const int ln = lane & 15, hi = lane >> 4;

    const half_t* wbase = whh16 + (size_t)dir * HID * HID;

    // A fragments in regs: afrag[mt][kk] = W[w*64+mt*16+ln][kk*32+hi*8 ..+8], kk<12
    half8 afrag[4][KK_REG];
    #pragma unroll
    for (int mt = 0; mt < 4; ++mt) {
        #pragma unroll
        for (int kk = 0; kk < KK_REG; ++kk)
            afrag[mt][kk] = *(const half8*)(wbase + (size_t)(w*64 + mt*16 + ln)*HID + kk*32 + hi*8);
    }

    // stage W k-tail [384,512) k-major: row j, 16B chunk c8 -> kt=c8>>2, full-rank chunk XOR
    for (int idx = threadIdx.x; idx < HID*16; idx += 512) {
        int row = idx >> 4, c8 = idx & 15;
        int off = ((((c8 & 3) ^ (row & 3) ^ ((row >> 2) & 3)) << 4));
        *(half8*)(wlds + (c8 >> 2)*32768 + row*64 + off) =
            *(const half8*)(wbase + (size_t)row*HID + K_REG + c8*8);
    }

    const int b  = bg*16 + ln;       // this lane's batch column
    const int jq = w*64 + hi*4;      // j quad base; mt adds 16

    const ptrdiff_t dstep = dir ? -(ptrdiff_t)(BATCH*2*HID) : (ptrdiff_t)(BATCH*2*HID);
    const int t0 = dir ? (SEQ-1) : 0;
    const size_t base0 = ((size_t)(t0*BATCH + b))*(2*HID) + (size_t)dir*HID + jq;
    const half_t* xb = xp + base0;
    half_t*       op = outbuf + base0;

    // per-lane LDS bases (full-rank XOR folded; per-access adders bits>=10 -> imm offsets)
    const int swz = ((hi ^ (ln & 3) ^ ((ln >> 2) & 3)) << 4);
    const char* hrdL = hlds + ln*64 + swz;              // + buf*16384 + kk*1024
    const char* wrdL = wlds + (w*64 + ln)*64 + swz;     // + kt*32768 + mt*1024
    char*       hwrL = hlds + (w*2)*1024 + ln*64;       // + buf*16384 + (mt>>1)*1024 + woff
    const int woff0 = ((((hi >> 1) ^ (ln & 3) ^ ((ln >> 2) & 3)) << 4)) + (hi & 1)*8;
    const int woff1 = woff0 ^ 32;

    // ---- step 0: h == 0 -> acc = xq(t0); no h reads, no MFMA ----
    half4 xq[4];
    #pragma unroll
    for (int mt = 0; mt < 4; ++mt) xq[mt] = *(const half4*)(xb + mt*16);
    xb += dstep;

    floatx4 acc[4];
    #pragma unroll
    for (int mt = 0; mt < 4; ++mt) {
        acc[mt][0] = (float)xq[mt][0]; acc[mt][1] = (float)xq[mt][1];
        acc[mt][2] = (float)xq[mt][2]; acc[mt][3] = (float)xq[mt][3];
    }
    // prefetch xq(t1)
    #pragma unroll
    for (int mt = 0; mt < 4; ++mt) xq[mt] = *(const half4*)(xb + mt*16);
    xb += dstep;

    {
        half4 hv[4];
        #pragma unroll
        for (int mt = 0; mt < 4; ++mt) {
            #pragma unroll
            for (int r = 0; r < 4; ++r)
                hv[mt][r] = (_Float16)fmaxf(acc[mt][r], 0.f);
            *(half4*)(hwrL + (mt >> 1)*1024 + ((mt & 1) ? woff1 : woff0)) = hv[mt];  // buf 0
            *(half4*)(op + mt*16) = hv[mt];
        }
        op += dstep;
    }
    // pre-barrier seed for step 1 (xq = xp(t1)); issue xq(t2) loads
    #pragma unroll
    for (int mt = 0; mt < 4; ++mt) {
        acc[mt][0] = (float)xq[mt][0]; acc[mt][1] = (float)xq[mt][1];
        acc[mt][2] = (float)xq[mt][2]; acc[mt][3] = (float)xq[mt][3];
    }
    #pragma unroll
    for (int mt = 0; mt < 4; ++mt) xq[mt] = *(const half4*)(xb + mt*16);
    xb += dstep;
    // publish wlds staging + step-0 h writes
    asm volatile("s_waitcnt lgkmcnt(0)\n\ts_barrier" ::: "memory");

    for (int step = 1; step < SEQ; ++step) {
        const int rb = (step + 1) & 1;   // buffer holding h from previous step
        const int wb = step & 1;         // buffer to write h of this step
        const char* hrd = hrdL + rb*HBUF_BYTES;

        // acc already seeded pre-barrier; post-barrier region starts with reads+MFMAs
        __builtin_amdgcn_s_setprio(1);
        // ---- k < 384: W in regs, h from LDS (2-deep paired pipeline, imm offsets) ----
        half8 c0 = *(const half8*)(hrd + 0*1024);
        half8 c1 = *(const half8*)(hrd + 1*1024);
        #pragma unroll
        for (int g = 0; g < 5; ++g) {
            half8 n0 = *(const half8*)(hrd + (2*g+2)*1024);
            half8 n1 = *(const half8*)(hrd + (2*g+3)*1024);
            #pragma unroll
            for (int mt = 0; mt < 4; ++mt)
                acc[mt] = __builtin_amdgcn_mfma_f32_16x16x32_f16(afrag[mt][2*g],   c0, acc[mt], 0, 0, 0);
            #pragma unroll
            for (int mt = 0; mt < 4; ++mt)
                acc[mt] = __builtin_amdgcn_mfma_f32_16x16x32_f16(afrag[mt][2*g+1], c1, acc[mt], 0, 0, 0);
            c0 = n0; c1 = n1;
        }
        // preload W-tail kt=0 group (ch + 4 w) in the shadow of the kk=10/11 MFMAs
        half8 chA = *(const half8*)(hrd + 12*1024);
        half8 wA0 = *(const half8*)(wrdL + 0*32768 + 0*1024);
        half8 wA1 = *(const half8*)(wrdL + 0*32768 + 1*1024);
        half8 wA2 = *(const half8*)(wrdL + 0*32768 + 2*1024);
        half8 wA3 = *(const half8*)(wrdL + 0*32768 + 3*1024);
        #pragma unroll
        for (int mt = 0; mt < 4; ++mt)
            acc[mt] = __builtin_amdgcn_mfma_f32_16x16x32_f16(afrag[mt][10], c0, acc[mt], 0, 0, 0);
        #pragma unroll
        for (int mt = 0; mt < 4; ++mt)
            acc[mt] = __builtin_amdgcn_mfma_f32_16x16x32_f16(afrag[mt][11], c1, acc[mt], 0, 0, 0);

        // ---- k in [384,512): hand-pipelined 2-deep, rotating A/B name sets ----
        half8 chB = *(const half8*)(hrd + 13*1024);
        half8 wB0 = *(const half8*)(wrdL + 1*32768 + 0*1024);
        half8 wB1 = *(const half8*)(wrdL + 1*32768 + 1*1024);
        acc[0] = __builtin_amdgcn_mfma_f32_16x16x32_f16(wA0, chA, acc[0], 0, 0, 0);
        acc[1] = __builtin_amdgcn_mfma_f32_16x16x32_f16(wA1, chA, acc[1], 0, 0, 0);
        half8 wB2 = *(const half8*)(wrdL + 1*32768 + 2*1024);
        half8 wB3 = *(const half8*)(wrdL + 1*32768 + 3*1024);
        acc[2] = __builtin_amdgcn_mfma_f32_16x16x32_f16(wA2, chA, acc[2], 0, 0, 0);
        acc[3] = __builtin_amdgcn_mfma_f32_16x16x32_f16(wA3, chA, acc[3], 0, 0, 0);
        chA = *(const half8*)(hrd + 14*1024);
        wA0 = *(const half8*)(wrdL + 2*32768 + 0*1024);
        wA1 = *(const half8*)(wrdL + 2*32768 + 1*1024);
        acc[0] = __builtin_amdgcn_mfma_f32_16x16x32_f16(wB0, chB, acc[0], 0, 0, 0);
        acc[1] = __builtin_amdgcn_mfma_f32_16x16x32_f16(wB1, chB, acc[1], 0, 0, 0);
        wA2 = *(const half8*)(wrdL + 2*32768 + 2*1024);
        wA3 = *(const half8*)(wrdL + 2*32768 + 3*1024);
        acc[2] = __builtin_amdgcn_mfma_f32_16x16x32_f16(wB2, chB, acc[2], 0, 0, 0);
        acc[3] = __builtin_amdgcn_mfma_f32_16x16x32_f16(wB3, chB, acc[3], 0, 0, 0);
        chB = *(const half8*)(hrd + 15*1024);
        wB0 = *(const half8*)(wrdL + 3*32768 + 0*1024);
        wB1 = *(const half8*)(wrdL + 3*32768 + 1*1024);
        acc[0] = __builtin_amdgcn_mfma_f32_16x16x32_f16(wA0, chA, acc[0], 0, 0, 0);
        acc[1] = __builtin_amdgcn_mfma_f32_16x16x32_f16(wA1, chA, acc[1], 0, 0, 0);
        wB2 = *(const half8*)(wrdL + 3*32768 + 2*1024);
        wB3 = *(const half8*)(wrdL + 3*32768 + 3*1024);
        acc[2] = __builtin_amdgcn_mfma_f32_16x16x32_f16(wA2, chA, acc[2], 0, 0, 0);
        acc[3] = __builtin_amdgcn_mfma_f32_16x16x32_f16(wA3, chA, acc[3], 0, 0, 0);
        acc[0] = __builtin_amdgcn_mfma_f32_16x16x32_f16(wB0, chB, acc[0], 0, 0, 0);
        acc[1] = __builtin_amdgcn_mfma_f32_16x16x32_f16(wB1, chB, acc[1], 0, 0, 0);
        acc[2] = __builtin_amdgcn_mfma_f32_16x16x32_f16(wB2, chB, acc[2], 0, 0, 0);
        acc[3] = __builtin_amdgcn_mfma_f32_16x16x32_f16(wB3, chB, acc[3], 0, 0, 0);
        __builtin_amdgcn_s_setprio(0);

        // ---- epilogue: hv = relu(acc); h-write ----
        half4 hv[4];
        #pragma unroll
        for (int mt = 0; mt < 4; ++mt) {
            #pragma unroll
            for (int r = 0; r < 4; ++r)
                hv[mt][r] = (_Float16)fmaxf(acc[mt][r], 0.f);
        }

        if (step + 1 < SEQ) {
            char* hw = hwrL + wb*HBUF_BYTES;
            #pragma unroll
            for (int mt = 0; mt < 4; ++mt)
                *(half4*)(hw + (mt >> 1)*1024 + ((mt & 1) ? woff1 : woff0)) = hv[mt];
            // pre-barrier: seed acc for step+1 from xq=xp(t(step+1)); issue xq(t(step+2))
            #pragma unroll
            for (int mt = 0; mt < 4; ++mt) {
                acc[mt][0] = (float)xq[mt][0]; acc[mt][1] = (float)xq[mt][1];
                acc[mt][2] = (float)xq[mt][2]; acc[mt][3] = (float)xq[mt][3];
            }
            if (step + 2 < SEQ) {
                #pragma unroll
                for (int mt = 0; mt < 4; ++mt) xq[mt] = *(const half4*)(xb + mt*16);
            }
            xb += dstep;
            // single barrier: publishes h(t+1) AND proves all reads of rb finished
            asm volatile("s_waitcnt lgkmcnt(0)\n\ts_barrier" ::: "memory");
        }

        // fire-and-forget global store (drained at kernel end)
        #pragma unroll
        for (int mt = 0; mt < 4; ++mt)
            *(half4*)(op + mt*16) = hv[mt];
        op += dstep;
    }
}

// ---------------- final FC: [16384,1024] x [18,1024]^T + b ----------------
__global__ __launch_bounds__(256)
void fc_kernel(const half_t* __restrict__ X, const half_t* __restrict__ W16,
               const float* __restrict__ bias, float* __restrict__ Y)
{
    __shared__ half8 Ws8[2304];   // 18*1024 half
    half_t* Ws = (half_t*)Ws8;
    for (int ch = threadIdx.x; ch < 2304; ch += 256)
        Ws8[ch] = *(const half8*)(W16 + (size_t)ch*8);
    __syncthreads();

    int wi = threadIdx.x >> 6, lane = threadIdx.x & 63;
    int m = blockIdx.x*4 + wi;
    const half_t* xr = X + (size_t)m*1024 + lane*16;
    half8 x0 = *(const half8*)xr;
    half8 x1 = *(const half8*)(xr + 8);
    float xa[16];
    #pragma unroll
    for (int i = 0; i < 8; ++i) { xa[i] = (float)x0[i]; xa[8+i] = (float)x1[i]; }

    for (int n = 0; n < NOUT; ++n) {
        const half_t* wr = Ws + n*1024 + lane*16;
        half8 w0 = *(const half8*)wr;
        half8 w1 = *(const half8*)(wr + 8);
        float s = 0.f;
        #pragma unroll
        for (int i = 0; i < 8; ++i) s += xa[i]*(float)w0[i] + xa[8+i]*(float)w1[i];
        #pragma unroll
        for (int off = 32; off > 0; off >>= 1) s += __shfl_down(s, off, 64);
        if (lane == 0) Y[(size_t)m*NOUT + n] = s + bias[n];
    }
}

// ---------------- launcher ----------------
extern "C" void kernel_launch(void* const* d_in, const int* in_sizes, int n_in,
                              void* d_out, int out_size, void* d_ws, size_t ws_size,
                              hipStream_t stream)
{
    const int*   text    = (const int*)  d_in[0];
    const float* emb     = (const float*)d_in[1];
    const float* emfc_w  = (const float*)d_in[2];
    const float* emfc_b  = (const float*)d_in[3];
    const float* w_ih0   = (const float*)d_in[4];
    const float* w_hh0   = (const float*)d_in[5];
    const float* b_ih0   = (const float*)d_in[6];
    const float* b_hh0   = (const float*)d_in[7];
    const float* w_ih1   = (const float*)d_in[8];
    const float* w_hh1   = (const float*)d_in[9];
    const float* b_ih1   = (const float*)d_in[10];
    const float* b_hh1   = (const float*)d_in[11];
    const float* fc_w    = (const float*)d_in[12];
    const float* fc_b    = (const float*)d_in[13];
    float* out = (float*)d_out;

    char* ws = (char*)d_ws;
    half_t* whh0_16 = (half_t*)(ws + O_WHH0_16);
    half_t* whh1_16 = (half_t*)(ws + O_WHH1_16);
    half_t* emfc16  = (half_t*)(ws + O_EMFC16);
    half_t* wih0    = (half_t*)(ws + O_WIH0);
    half_t* wih1    = (half_t*)(ws + O_WIH1);
    half_t* fc16    = (half_t*)(ws + O_FC16);
    half_t* pe      = (half_t*)(ws + O_PE);
    half_t* xp      = (half_t*)(ws + O_XP);
    half_t* out0    = (half_t*)(ws + O_OUT);
    half_t* out1    = (half_t*)(ws + O_OUT);   // aliased: out0 dead once xp1 GEMM done

    // one-time: allow full 160KB dynamic LDS for rnn_layer (host-side attr; capture-safe)
    static int attr_done = 0;
    if (!attr_done) {
        hipFuncSetAttribute((const void*)rnn_layer,
                            hipFuncAttributeMaxDynamicSharedMemorySize, LDS_BYTES);
        attr_done = 1;
    }

    // 1) weight conversions fp32->fp16 (fused, single launch)
    CvtJobs jobs;
    jobs.s[0] = emfc_w; jobs.d[0] = emfc16;  jobs.n8[0] = 8192;
    jobs.s[1] = w_ih0;  jobs.d[1] = wih0;    jobs.n8[1] = 32768;
    jobs.s[2] = w_ih1;  jobs.d[2] = wih1;    jobs.n8[2] = 131072;
    jobs.s[3] = w_hh0;  jobs.d[3] = whh0_16; jobs.n8[3] = 65536;
    jobs.s[4] = w_hh1;  jobs.d[4] = whh1_16; jobs.n8[4] = 65536;
    jobs.s[5] = fc_w;   jobs.d[5] = fc16;    jobs.n8[5] = 2304;
    cvt6<<<dim3(128, 6), 256, 0, stream>>>(jobs);

    // 2) post_emb = gather(emb, text) @ emfc_w^T + emfc_b
    gemm_nt<true><<<dim3(M_TOT/128, EMB/128), 256, 0, stream>>>(
        nullptr, emb, text, emfc16, emfc_b, nullptr, pe, M_TOT, EMB, EMB);

    // 3) xp0 = post_emb @ w_ih0^T + (b_ih0 + b_hh0)
    gemm_nt<false><<<dim3(M_TOT/128, (2*HID)/128), 256, 0, stream>>>(
        pe, nullptr, nullptr, wih0, b_ih0, b_hh0, xp, M_TOT, 2*HID, EMB);

    // 4) layer0 recurrence (8 independent blocks x 8 waves)
    rnn_layer<<<8, 512, LDS_BYTES, stream>>>(xp, out0, whh0_16);

    // 5) xp1 = out0 @ w_ih1^T + (b_ih1 + b_hh1)
    gemm_nt<false><<<dim3(M_TOT/128, (2*HID)/128), 256, 0, stream>>>(
        out0, nullptr, nullptr, wih1, b_ih1, b_hh1, xp, M_TOT, 2*HID, 2*HID);

    // 6) layer1 recurrence
    rnn_layer<<<8, 512, LDS_BYTES, stream>>>(xp, out1, whh1_16);

    // 7) out = out1 @ fc_w^T + fc_b
    fc_kernel<<<M_TOT/4, 256, 0, stream>>>(out1, fc16, fc_b, out);
}